// Round 3
// baseline (7842.873 us; speedup 1.0000x reference)
//
#include <hip/hip_runtime.h>
#include <math.h>

#define BB 4
#define NN 8192
#define GG 512
#define KK 32
#define DD 768
#define SS 513
#define HH 12

__device__ __forceinline__ float gelu_f(float x) {
  return 0.5f * x * (1.f + erff(x * 0.70710678118654752f));
}

// ---------------------------------------------------------------- FPS
// One block per batch. 1024 threads x 8 points each, xyz+dmin in registers.
// Exact-match strategy: no FMA contraction, argmax tiebreak = lowest index.
__global__ __launch_bounds__(1024) void fps_kernel(const float* __restrict__ pts,
                                                   int* __restrict__ fidx,
                                                   float* __restrict__ center) {
  int b = blockIdx.x;
  int tid = threadIdx.x;
  const float* P = pts + (size_t)b * NN * 3;
  float x[8], y[8], z[8], dmin[8];
#pragma unroll
  for (int j = 0; j < 8; j++) {
    int p = tid + 1024 * j;
    x[j] = P[p * 3 + 0]; y[j] = P[p * 3 + 1]; z[j] = P[p * 3 + 2];
    dmin[j] = 1e10f;
  }
  __shared__ unsigned long long sred[16];
  __shared__ int sfar;
  __shared__ float scx, scy, scz;
  int far = 0;
  for (int it = 0; it < GG; it++) {
    if (tid == 0) {
      float cx = P[far * 3 + 0], cy = P[far * 3 + 1], cz = P[far * 3 + 2];
      scx = cx; scy = cy; scz = cz;
      fidx[b * GG + it] = far;
      center[(size_t)(b * GG + it) * 3 + 0] = cx;
      center[(size_t)(b * GG + it) * 3 + 1] = cy;
      center[(size_t)(b * GG + it) * 3 + 2] = cz;
    }
    __syncthreads();
    float cx = scx, cy = scy, cz = scz;
    unsigned long long best = 0;
#pragma unroll
    for (int j = 0; j < 8; j++) {
      float dx = __fsub_rn(x[j], cx);
      float dy = __fsub_rn(y[j], cy);
      float dz = __fsub_rn(z[j], cz);
      float d = __fadd_rn(__fadd_rn(__fmul_rn(dx, dx), __fmul_rn(dy, dy)), __fmul_rn(dz, dz));
      float dm = fminf(dmin[j], d);
      dmin[j] = dm;
      unsigned long long key = ((unsigned long long)__float_as_uint(dm) << 32)
                             | (unsigned)(0xFFFFFFFFu - (unsigned)(tid + 1024 * j));
      best = (key > best) ? key : best;
    }
#pragma unroll
    for (int off = 32; off > 0; off >>= 1) {
      unsigned long long o = __shfl_xor(best, off);
      best = (o > best) ? o : best;
    }
    int lane = tid & 63, wid = tid >> 6;
    if (lane == 0) sred[wid] = best;
    __syncthreads();
    if (tid < 16) {
      unsigned long long v = sred[tid];
#pragma unroll
      for (int off = 8; off > 0; off >>= 1) {
        unsigned long long o = __shfl_xor(v, off);
        v = (o > v) ? o : v;
      }
      if (tid == 0) sfar = (int)(0xFFFFFFFFu - (unsigned)(v & 0xFFFFFFFFu));
    }
    __syncthreads();
    far = sfar;
  }
}

// ---------------------------------------------------------------- KNN
// One block per (b,g). Distances in LDS; 32 rounds of masked argmin.
// Only the SET of 32 NN matters downstream (max-pool invariance).
__global__ __launch_bounds__(256) void knn_kernel(const float* __restrict__ pts,
                                                  const float* __restrict__ center,
                                                  int* __restrict__ knn_idx) {
  int bg = blockIdx.x;
  int b = bg >> 9;
  int tid = threadIdx.x;
  __shared__ float dist[NN];
  __shared__ unsigned long long sred[4];
  const float* P = pts + (size_t)b * NN * 3;
  float cx = center[bg * 3 + 0], cy = center[bg * 3 + 1], cz = center[bg * 3 + 2];
  for (int j = 0; j < 32; j++) {
    int p = tid + 256 * j;
    float dx = P[p * 3 + 0] - cx, dy = P[p * 3 + 1] - cy, dz = P[p * 3 + 2] - cz;
    dist[p] = dx * dx + dy * dy + dz * dz;
  }
  __syncthreads();
  for (int r = 0; r < KK; r++) {
    unsigned long long best = 0xFFFFFFFFFFFFFFFFull;
#pragma unroll 8
    for (int j = 0; j < 32; j++) {
      int p = tid + 256 * j;
      unsigned long long key = ((unsigned long long)__float_as_uint(dist[p]) << 32) | (unsigned)p;
      best = (key < best) ? key : best;
    }
#pragma unroll
    for (int off = 32; off > 0; off >>= 1) {
      unsigned long long o = __shfl_xor(best, off);
      best = (o < best) ? o : best;
    }
    int lane = tid & 63, wid = tid >> 6;
    if (lane == 0) sred[wid] = best;
    __syncthreads();
    if (tid < 4) {
      unsigned long long v = sred[tid];
      unsigned long long o = __shfl_xor(v, 1); v = (o < v) ? o : v;
      o = __shfl_xor(v, 2); v = (o < v) ? o : v;
      if (tid == 0) {
        int p = (int)(v & 0xFFFFFFFFu);
        knn_idx[bg * KK + r] = p;
        dist[p] = 3.0e38f;   // mask
      }
    }
    __syncthreads();
  }
}

// ---------------------------------------------------------------- Encoder
// One block per group: feat(32x6) -> f1(32x128) -> f2(32x256) -> fg ->
// f3(32x512) -> f4(32x256) -> tok(256). Weight tiles staged via 16KB wst.
// Static LDS ~134KB (gfx950 allows up to 160KB/workgroup).
__global__ __launch_bounds__(256) void encoder_kernel(
    const float* __restrict__ pts, const float* __restrict__ colors,
    const int* __restrict__ knn_idx, const float* __restrict__ center,
    const float* __restrict__ w1a, const float* __restrict__ b1a,
    const float* __restrict__ bn1g, const float* __restrict__ bn1b,
    const float* __restrict__ bn1m, const float* __restrict__ bn1v,
    const float* __restrict__ w1b, const float* __restrict__ b1b,
    const float* __restrict__ w2a, const float* __restrict__ b2a,
    const float* __restrict__ bn2g, const float* __restrict__ bn2b,
    const float* __restrict__ bn2m, const float* __restrict__ bn2v,
    const float* __restrict__ w2b, const float* __restrict__ b2b,
    float* __restrict__ tok)
{
  int bg = blockIdx.x;
  int b = bg >> 9;
  int tid = threadIdx.x;
  __shared__ float feat[KK][8];
  __shared__ float f1[KK][132];
  __shared__ float f2[KK][260];   // later reused as f4
  __shared__ float fgs[256];
  __shared__ float f3[KK][516];
  __shared__ float wst[4096];
  if (tid < 192) {
    int k = tid / 6, c = tid % 6;
    int p = knn_idx[bg * KK + k];
    float v;
    if (c < 3) v = pts[(size_t)(b * NN + p) * 3 + c] - center[bg * 3 + c];
    else       v = colors[(size_t)(b * NN + p) * 3 + (c - 3)];
    feat[k][c] = v;
  }
  __syncthreads();
  // stage 1a: 32x6 @ 6x128 + bn + relu
  for (int e = tid; e < KK * 128; e += 256) {
    int k = e >> 7, j = e & 127;
    float s = b1a[j];
#pragma unroll
    for (int c = 0; c < 6; c++) s += feat[k][c] * w1a[j * 6 + c];
    s = (s - bn1m[j]) * rsqrtf(bn1v[j] + 1e-5f) * bn1g[j] + bn1b[j];
    f1[k][j] = fmaxf(s, 0.f);
  }
  __syncthreads();
  // stage 1b: f2 = f1 @ w1b^T + b1b   (K=128, out 256), 8 tiles of 32 j
  {
    int k = tid >> 3, jg = tid & 7;
    for (int jt = 0; jt < 8; jt++) {
      __syncthreads();
      for (int e = tid; e < 32 * 128; e += 256) {
        int jj = e >> 7, c = e & 127;
        wst[c * 32 + jj] = w1b[(size_t)(jt * 32 + jj) * 128 + c];
      }
      __syncthreads();
      float a0 = 0, a1 = 0, a2 = 0, a3 = 0;
#pragma unroll 4
      for (int c = 0; c < 128; c++) {
        float a = f1[k][c];
        const float* w = &wst[c * 32 + jg * 4];
        a0 += a * w[0]; a1 += a * w[1]; a2 += a * w[2]; a3 += a * w[3];
      }
      int j = jt * 32 + jg * 4;
      f2[k][j + 0] = a0 + b1b[j + 0];
      f2[k][j + 1] = a1 + b1b[j + 1];
      f2[k][j + 2] = a2 + b1b[j + 2];
      f2[k][j + 3] = a3 + b1b[j + 3];
    }
  }
  __syncthreads();
  { // fg = max_k f2
    float m = -3e38f;
    for (int k = 0; k < KK; k++) m = fmaxf(m, f2[k][tid]);
    fgs[tid] = m;
  }
  __syncthreads();
  // stage 2a: f3[k][j] = relu(bn2( sum_c in[k][c]*w2a[j][c] + b2a[j] ))
  // in = [fg(256) | f2(256)]
  {
    int kg = tid >> 4, jg = tid & 15;
    for (int jt = 0; jt < 8; jt++) {
      float acc[2][4] = {{0, 0, 0, 0}, {0, 0, 0, 0}};
      for (int ct = 0; ct < 8; ct++) {
        __syncthreads();
        for (int e = tid; e < 64 * 64; e += 256) {
          int jj = e >> 6, c = e & 63;
          wst[c * 64 + jj] = w2a[(size_t)(jt * 64 + jj) * 512 + ct * 64 + c];
        }
        __syncthreads();
        int cbase = ct * 64;
        if (cbase < 256) {
#pragma unroll 4
          for (int c = 0; c < 64; c++) {
            float a = fgs[cbase + c];
            const float* w = &wst[c * 64 + jg * 4];
            acc[0][0] += a * w[0]; acc[0][1] += a * w[1]; acc[0][2] += a * w[2]; acc[0][3] += a * w[3];
            acc[1][0] += a * w[0]; acc[1][1] += a * w[1]; acc[1][2] += a * w[2]; acc[1][3] += a * w[3];
          }
        } else {
#pragma unroll 2
          for (int c = 0; c < 64; c++) {
            float a0 = f2[kg * 2 + 0][cbase - 256 + c];
            float a1 = f2[kg * 2 + 1][cbase - 256 + c];
            const float* w = &wst[c * 64 + jg * 4];
            acc[0][0] += a0 * w[0]; acc[0][1] += a0 * w[1]; acc[0][2] += a0 * w[2]; acc[0][3] += a0 * w[3];
            acc[1][0] += a1 * w[0]; acc[1][1] += a1 * w[1]; acc[1][2] += a1 * w[2]; acc[1][3] += a1 * w[3];
          }
        }
      }
#pragma unroll
      for (int i = 0; i < 2; i++)
#pragma unroll
        for (int jj = 0; jj < 4; jj++) {
          int j = jt * 64 + jg * 4 + jj;
          float s = acc[i][jj] + b2a[j];
          s = (s - bn2m[j]) * rsqrtf(bn2v[j] + 1e-5f) * bn2g[j] + bn2b[j];
          f3[kg * 2 + i][j] = fmaxf(s, 0.f);
        }
    }
  }
  __syncthreads();
  // stage 2b: f4 = f3 @ w2b^T + b2b (K=512, out 256); f4 into f2 arena
  {
    int kg = tid >> 4, jg = tid & 15;
    for (int jt = 0; jt < 4; jt++) {
      float acc[2][4] = {{0, 0, 0, 0}, {0, 0, 0, 0}};
      for (int ct = 0; ct < 8; ct++) {
        __syncthreads();
        for (int e = tid; e < 64 * 64; e += 256) {
          int jj = e >> 6, c = e & 63;
          wst[c * 64 + jj] = w2b[(size_t)(jt * 64 + jj) * 512 + ct * 64 + c];
        }
        __syncthreads();
#pragma unroll 2
        for (int c = 0; c < 64; c++) {
          float a0 = f3[kg * 2 + 0][ct * 64 + c];
          float a1 = f3[kg * 2 + 1][ct * 64 + c];
          const float* w = &wst[c * 64 + jg * 4];
          acc[0][0] += a0 * w[0]; acc[0][1] += a0 * w[1]; acc[0][2] += a0 * w[2]; acc[0][3] += a0 * w[3];
          acc[1][0] += a1 * w[0]; acc[1][1] += a1 * w[1]; acc[1][2] += a1 * w[2]; acc[1][3] += a1 * w[3];
        }
      }
#pragma unroll
      for (int i = 0; i < 2; i++)
#pragma unroll
        for (int jj = 0; jj < 4; jj++) {
          int j = jt * 64 + jg * 4 + jj;
          f2[kg * 2 + i][j] = acc[i][jj] + b2b[j];
        }
    }
  }
  __syncthreads();
  { // tok = max_k f4
    float m = -3e38f;
    for (int k = 0; k < KK; k++) m = fmaxf(m, f2[k][tid]);
    tok[(size_t)bg * 256 + tid] = m;
  }
}

// ---------------------------------------------------------------- generic GEMM
// out[M,N] = act(A[M,K] @ W + bias) (+ resid). TRANSB: W is [N,K] row-major.
// 64x64 tile, 256 threads, 4x4 per thread, K-step 16.
template <int TRANSB, int ACT, int RESID>
__global__ __launch_bounds__(256) void gemm_kernel(
    const float* __restrict__ A, const float* __restrict__ W,
    const float* __restrict__ bias, const float* __restrict__ resid,
    float* __restrict__ out, int M, int N, int K)
{
  __shared__ float As[16][64];
  __shared__ float Bs[16][64];
  int tile_n = blockIdx.x * 64, tile_m = blockIdx.y * 64;
  int tid = threadIdx.x;
  int tm = tid >> 4, tn = tid & 15;
  float acc[4][4] = {};
  for (int k0 = 0; k0 < K; k0 += 16) {
    {
      int e = tid * 4;
      int m = e >> 4, k = e & 15;
      int row = tile_m + m;
      float4 v = make_float4(0.f, 0.f, 0.f, 0.f);
      if (row < M) v = *reinterpret_cast<const float4*>(&A[(size_t)row * K + k0 + k]);
      As[k + 0][m] = v.x; As[k + 1][m] = v.y; As[k + 2][m] = v.z; As[k + 3][m] = v.w;
    }
    if (TRANSB == 0) {
      int e = tid * 4;
      int n = e & 63, k = e >> 6;
      float4 v = *reinterpret_cast<const float4*>(&W[(size_t)(k0 + k) * N + tile_n + n]);
      *reinterpret_cast<float4*>(&Bs[k][n]) = v;
    } else {
      int e = tid * 4;
      int k = e & 15, n = e >> 4;
      float4 v = *reinterpret_cast<const float4*>(&W[(size_t)(tile_n + n) * K + k0 + k]);
      Bs[k + 0][n] = v.x; Bs[k + 1][n] = v.y; Bs[k + 2][n] = v.z; Bs[k + 3][n] = v.w;
    }
    __syncthreads();
#pragma unroll
    for (int kk = 0; kk < 16; kk++) {
      float4 a = *reinterpret_cast<const float4*>(&As[kk][tm * 4]);
      float4 w = *reinterpret_cast<const float4*>(&Bs[kk][tn * 4]);
      acc[0][0] += a.x * w.x; acc[0][1] += a.x * w.y; acc[0][2] += a.x * w.z; acc[0][3] += a.x * w.w;
      acc[1][0] += a.y * w.x; acc[1][1] += a.y * w.y; acc[1][2] += a.y * w.z; acc[1][3] += a.y * w.w;
      acc[2][0] += a.z * w.x; acc[2][1] += a.z * w.y; acc[2][2] += a.z * w.z; acc[2][3] += a.z * w.w;
      acc[3][0] += a.w * w.x; acc[3][1] += a.w * w.y; acc[3][2] += a.w * w.z; acc[3][3] += a.w * w.w;
    }
    __syncthreads();
  }
#pragma unroll
  for (int i = 0; i < 4; i++) {
    int row = tile_m + tm * 4 + i;
    if (row >= M) continue;
    int col = tile_n + tn * 4;
    float4 r;
    r.x = acc[i][0] + bias[col + 0];
    r.y = acc[i][1] + bias[col + 1];
    r.z = acc[i][2] + bias[col + 2];
    r.w = acc[i][3] + bias[col + 3];
    if (ACT == 1) { r.x = gelu_f(r.x); r.y = gelu_f(r.y); r.z = gelu_f(r.z); r.w = gelu_f(r.w); }
    if (RESID) {
      float4 rr = *reinterpret_cast<const float4*>(&resid[(size_t)row * N + col]);
      r.x += rr.x; r.y += rr.y; r.z += rr.z; r.w += rr.w;
    }
    *reinterpret_cast<float4*>(&out[(size_t)row * N + col]) = r;
  }
}

// ---------------------------------------------------------------- LayerNorm
__global__ __launch_bounds__(256) void ln_kernel(const float* __restrict__ x,
                                                 const float* __restrict__ g,
                                                 const float* __restrict__ bta,
                                                 float* __restrict__ y) {
  int r = blockIdx.x;
  int tid = threadIdx.x;
  __shared__ float sred[4];
  __shared__ float smu, srs;
  const float* xr = x + (size_t)r * 768;
  float v0 = xr[tid], v1 = xr[tid + 256], v2 = xr[tid + 512];
  float s = v0 + v1 + v2;
#pragma unroll
  for (int off = 32; off > 0; off >>= 1) s += __shfl_xor(s, off);
  if ((tid & 63) == 0) sred[tid >> 6] = s;
  __syncthreads();
  if (tid < 4) {
    float t = sred[tid];
    t += __shfl_xor(t, 1); t += __shfl_xor(t, 2);
    if (tid == 0) smu = t * (1.f / 768.f);
  }
  __syncthreads();
  float mu = smu;
  float d0 = v0 - mu, d1 = v1 - mu, d2 = v2 - mu;
  float ss = d0 * d0 + d1 * d1 + d2 * d2;
#pragma unroll
  for (int off = 32; off > 0; off >>= 1) ss += __shfl_xor(ss, off);
  if ((tid & 63) == 0) sred[tid >> 6] = ss;
  __syncthreads();
  if (tid < 4) {
    float t = sred[tid];
    t += __shfl_xor(t, 1); t += __shfl_xor(t, 2);
    if (tid == 0) srs = rsqrtf(t * (1.f / 768.f) + 1e-5f);
  }
  __syncthreads();
  float rs = srs;
  float* yr = y + (size_t)r * 768;
  yr[tid]       = d0 * rs * g[tid]       + bta[tid];
  yr[tid + 256] = d1 * rs * g[tid + 256] + bta[tid + 256];
  yr[tid + 512] = d2 * rs * g[tid + 512] + bta[tid + 512];
}

// ---------------------------------------------------------------- pos-embed hidden
__global__ __launch_bounds__(256) void pe_hidden_kernel(const float* __restrict__ center,
                                                        const float* __restrict__ w1,
                                                        const float* __restrict__ b1,
                                                        float* __restrict__ hid) {
  int e = blockIdx.x * 256 + threadIdx.x;   // 2048*128
  int r = e >> 7, j = e & 127;
  float cx = center[r * 3 + 0], cy = center[r * 3 + 1], cz = center[r * 3 + 2];
  float s = b1[j] + cx * w1[j * 3 + 0] + cy * w1[j * 3 + 1] + cz * w1[j * 3 + 2];
  hid[e] = gelu_f(s);
}

// ---------------------------------------------------------------- assemble xs
__global__ __launch_bounds__(256) void assemble_kernel(const float* __restrict__ tp,
                                                       const float* __restrict__ pp,
                                                       const float* __restrict__ cls_tok,
                                                       const float* __restrict__ cls_pos,
                                                       float* __restrict__ xs) {
  int r = blockIdx.x;   // 0..2051
  int b = r / SS, t = r % SS;
  int tid = threadIdx.x;
  float* xr = xs + (size_t)r * 768;
  if (t == 0) {
    for (int d = tid; d < 768; d += 256) xr[d] = cls_tok[d] + cls_pos[d];
  } else {
    int g = b * GG + (t - 1);
    for (int d = tid; d < 768; d += 256) xr[d] = tp[(size_t)g * 768 + d] + pp[(size_t)g * 768 + d];
  }
}

// ---------------------------------------------------------------- flash attention
// grid (9 qtiles, 12 heads, 4 batches), block 256 = 64 rows x 4 lanes.
// Q in registers (d-quarter per lane), cooperative dots, online softmax.
__global__ __launch_bounds__(256) void flash_kernel(const float* __restrict__ qkv,
                                                    float* __restrict__ o) {
  int qt = blockIdx.x, h = blockIdx.y, b = blockIdx.z;
  int tid = threadIdx.x;
  int rr = tid >> 2, cg = tid & 3;
  __shared__ float Ks[64][68];
  __shared__ float Vs[64][68];
  __shared__ float Ps[64][68];
  const float scale = 0.125f;
  int qrow = qt * 64 + rr;
  bool qvalid = qrow < SS;
  float q[16];
  {
    const float* qp = qkv + (size_t)(b * SS + (qvalid ? qrow : 0)) * 2304 + h * 64 + cg * 16;
#pragma unroll
    for (int i = 0; i < 16; i += 4) {
      float4 v = *reinterpret_cast<const float4*>(qp + i);
      q[i + 0] = qvalid ? v.x * scale : 0.f;
      q[i + 1] = qvalid ? v.y * scale : 0.f;
      q[i + 2] = qvalid ? v.z * scale : 0.f;
      q[i + 3] = qvalid ? v.w * scale : 0.f;
    }
  }
  float O[16];
#pragma unroll
  for (int i = 0; i < 16; i++) O[i] = 0.f;
  float mrow = -3e38f, lrow = 0.f;
  for (int kc = 0; kc < 9; kc++) {
    int kbase = kc * 64;
    for (int e = tid; e < 64 * 64; e += 256) {
      int krow = e >> 6, d = e & 63;
      int gk = kbase + krow;
      float kv = 0.f, vv = 0.f;
      if (gk < SS) {
        const float* pk = qkv + (size_t)(b * SS + gk) * 2304 + 768 + h * 64 + d;
        kv = *pk; vv = pk[768];
      }
      Ks[krow][d] = kv; Vs[krow][d] = vv;
    }
    __syncthreads();
    float svals[16];
    float mc = -3e38f;
    for (int kk = 0; kk < 64; kk++) {
      const float* kr = &Ks[kk][cg * 16];
      float p = 0.f;
#pragma unroll
      for (int i = 0; i < 16; i++) p += q[i] * kr[i];
      p += __shfl_xor(p, 1);
      p += __shfl_xor(p, 2);
      float s = (kbase + kk < SS) ? p : -3e38f;
      if ((kk & 3) == cg) svals[kk >> 2] = s;
      mc = fmaxf(mc, s);
    }
    float mnew = fmaxf(mrow, mc);
    float alpha = __expf(mrow - mnew);
    float lsum = 0.f;
#pragma unroll
    for (int jj = 0; jj < 16; jj++) {
      float pexp = __expf(svals[jj] - mnew);
      lsum += pexp;
      Ps[rr][jj * 4 + cg] = pexp;
    }
    lsum += __shfl_xor(lsum, 1);
    lsum += __shfl_xor(lsum, 2);
    lrow = lrow * alpha + lsum;
#pragma unroll
    for (int i = 0; i < 16; i++) O[i] *= alpha;
    mrow = mnew;
    __syncthreads();
#pragma unroll 4
    for (int kk = 0; kk < 64; kk++) {
      float pw = Ps[rr][kk];
      const float* vr = &Vs[kk][cg * 16];
#pragma unroll
      for (int i = 0; i < 16; i++) O[i] += pw * vr[i];
    }
    __syncthreads();
  }
  if (qvalid) {
    float inv = 1.f / lrow;
    float* op = o + (size_t)(b * SS + qrow) * 768 + h * 64 + cg * 16;
#pragma unroll
    for (int i = 0; i < 16; i++) op[i] = O[i] * inv;
  }
}

// ---------------------------------------------------------------- launch
extern "C" void kernel_launch(void* const* d_in, const int* in_sizes, int n_in,
                              void* d_out, int out_size, void* d_ws, size_t ws_size,
                              hipStream_t stream) {
  const float* pts    = (const float*)d_in[0];
  const float* colors = (const float*)d_in[1];
  const float* w1a    = (const float*)d_in[2];
  const float* b1a    = (const float*)d_in[3];
  const float* bn1g   = (const float*)d_in[4];
  const float* bn1b   = (const float*)d_in[5];
  const float* bn1m   = (const float*)d_in[6];
  const float* bn1v   = (const float*)d_in[7];
  const float* w1b    = (const float*)d_in[8];
  const float* b1b    = (const float*)d_in[9];
  const float* w2a    = (const float*)d_in[10];
  const float* b2a    = (const float*)d_in[11];
  const float* bn2g   = (const float*)d_in[12];
  const float* bn2b   = (const float*)d_in[13];
  const float* bn2m   = (const float*)d_in[14];
  const float* bn2v   = (const float*)d_in[15];
  const float* w2b    = (const float*)d_in[16];
  const float* b2b    = (const float*)d_in[17];
  const float* e2t_w  = (const float*)d_in[18];
  const float* e2t_b  = (const float*)d_in[19];
  const float* cls_token = (const float*)d_in[20];
  const float* cls_pos   = (const float*)d_in[21];
  const float* pe_w1  = (const float*)d_in[22];
  const float* pe_b1  = (const float*)d_in[23];
  const float* pe_w2  = (const float*)d_in[24];
  const float* pe_b2  = (const float*)d_in[25];
  const float* ln1_g  = (const float*)d_in[26];
  const float* ln1_b  = (const float*)d_in[27];
  const float* qkv_w  = (const float*)d_in[28];
  const float* qkv_b  = (const float*)d_in[29];
  const float* proj_w = (const float*)d_in[30];
  const float* proj_b = (const float*)d_in[31];
  const float* ln2_g  = (const float*)d_in[32];
  const float* ln2_b  = (const float*)d_in[33];
  const float* mlp_w1 = (const float*)d_in[34];
  const float* mlp_b1 = (const float*)d_in[35];
  const float* mlp_w2 = (const float*)d_in[36];
  const float* mlp_b2 = (const float*)d_in[37];
  const float* fcn_g  = (const float*)d_in[38];
  const float* fcn_b  = (const float*)d_in[39];
  const float* t2e_w  = (const float*)d_in[40];
  const float* t2e_b  = (const float*)d_in[41];

  // Lifetime-aliased workspace (total ~36.4 MB):
  //   persistent: fidx/center/knn, xs, hbuf
  //   region R (25.2 MB) reused three ways:
  //     phase 1 (pre-transformer): tok | hid | tp | pp
  //     phase 2 (attention):       qkvb | obuf   (dead once proj writes xs)
  //     phase 3 (MLP):             mh
  char* ws = (char*)d_ws;
  int*   fidx   = (int*)(ws + 0);                 //  8 KB
  float* center = (float*)(ws + 8192);            // 24 KB
  int*   knn    = (int*)(ws + 32768);             // 256 KB
  float* xs     = (float*)(ws + 294912);          // 6.30 MB (2052*768*4)
  float* hbuf   = (float*)(ws + 6598656);         // 6.30 MB
  char*  R      = ws + 12902400;                  // 25.21 MB region
  float* tok    = (float*)(R + 0);                // 2 MB  (2048*256*4)
  float* hid    = (float*)(R + 2097152);          // 1 MB  (2048*128*4)
  float* tp     = (float*)(R + 3145728);          // 6.29 MB (2048*768*4)
  float* pp     = (float*)(R + 9437184);          // 6.29 MB
  float* qkvb   = (float*)(R + 0);                // 18.91 MB (2052*2304*4)
  float* obuf   = (float*)(R + 18911232);         // 6.30 MB
  float* mh     = (float*)(R + 0);                // 25.21 MB (2052*3072*4)
  // end of R = 12902400 + 25214976 = 38117376 bytes total

  fps_kernel<<<BB, 1024, 0, stream>>>(pts, fidx, center);
  knn_kernel<<<BB * GG, 256, 0, stream>>>(pts, center, knn);
  encoder_kernel<<<BB * GG, 256, 0, stream>>>(pts, colors, knn, center,
      w1a, b1a, bn1g, bn1b, bn1m, bn1v, w1b, b1b,
      w2a, b2a, bn2g, bn2b, bn2m, bn2v, w2b, b2b, tok);
  gemm_kernel<1, 0, 0><<<dim3(12, 32), 256, 0, stream>>>(tok, e2t_w, e2t_b, nullptr, tp, 2048, 768, 256);
  pe_hidden_kernel<<<1024, 256, 0, stream>>>(center, pe_w1, pe_b1, hid);
  gemm_kernel<1, 0, 0><<<dim3(12, 32), 256, 0, stream>>>(hid, pe_w2, pe_b2, nullptr, pp, 2048, 768, 128);
  assemble_kernel<<<BB * SS, 256, 0, stream>>>(tp, pp, cls_token, cls_pos, xs);

  for (int i = 0; i < 4; i++) {
    ln_kernel<<<BB * SS, 256, 0, stream>>>(xs, ln1_g + i * 768, ln1_b + i * 768, hbuf);
    gemm_kernel<0, 0, 0><<<dim3(36, 33), 256, 0, stream>>>(hbuf, qkv_w + (size_t)i * 768 * 2304,
        qkv_b + i * 2304, nullptr, qkvb, 2052, 2304, 768);
    flash_kernel<<<dim3(9, 12, 4), 256, 0, stream>>>(qkvb, obuf);
    gemm_kernel<0, 0, 1><<<dim3(12, 33), 256, 0, stream>>>(obuf, proj_w + (size_t)i * 768 * 768,
        proj_b + i * 768, xs, xs, 2052, 768, 768);
    ln_kernel<<<BB * SS, 256, 0, stream>>>(xs, ln2_g + i * 768, ln2_b + i * 768, hbuf);
    gemm_kernel<0, 1, 0><<<dim3(48, 33), 256, 0, stream>>>(hbuf, mlp_w1 + (size_t)i * 768 * 3072,
        mlp_b1 + i * 3072, nullptr, mh, 2052, 3072, 768);
    gemm_kernel<0, 0, 1><<<dim3(12, 33), 256, 0, stream>>>(mh, mlp_w2 + (size_t)i * 3072 * 768,
        mlp_b2 + i * 768, xs, xs, 2052, 768, 3072);
  }
  ln_kernel<<<BB * SS, 256, 0, stream>>>(xs, fcn_g, fcn_b, hbuf);
  gemm_kernel<1, 0, 0><<<dim3(12, 33), 256, 0, stream>>>(hbuf, t2e_w, t2e_b, nullptr,
      (float*)d_out, 2052, 768, 768);
}

// Round 4
// 2981.763 us; speedup vs baseline: 2.6303x; 2.6303x over previous
//
#include <hip/hip_runtime.h>
#include <math.h>

#define BB 4
#define NN 8192
#define GG 512
#define KK 32
#define DD 768
#define SS 513
#define HH 12

typedef __attribute__((ext_vector_type(8))) short bf16x8;
typedef __attribute__((ext_vector_type(4))) float f32x4;

__device__ __forceinline__ float gelu_f(float x) {
  return 0.5f * x * (1.f + erff(x * 0.70710678118654752f));
}
__device__ __forceinline__ unsigned short f2b(float f) {
  unsigned u = __float_as_uint(f);
  u = (u + 0x7FFFu + ((u >> 16) & 1u)) >> 16;
  return (unsigned short)u;
}
__device__ __forceinline__ float b2f(unsigned short h) {
  return __uint_as_float(((unsigned)h) << 16);
}

// ---------------------------------------------------------------- FPS (unchanged)
__global__ __launch_bounds__(1024) void fps_kernel(const float* __restrict__ pts,
                                                   int* __restrict__ fidx,
                                                   float* __restrict__ center) {
  int b = blockIdx.x;
  int tid = threadIdx.x;
  const float* P = pts + (size_t)b * NN * 3;
  float x[8], y[8], z[8], dmin[8];
#pragma unroll
  for (int j = 0; j < 8; j++) {
    int p = tid + 1024 * j;
    x[j] = P[p * 3 + 0]; y[j] = P[p * 3 + 1]; z[j] = P[p * 3 + 2];
    dmin[j] = 1e10f;
  }
  __shared__ unsigned long long sred[16];
  __shared__ int sfar;
  __shared__ float scx, scy, scz;
  int far = 0;
  for (int it = 0; it < GG; it++) {
    if (tid == 0) {
      float cx = P[far * 3 + 0], cy = P[far * 3 + 1], cz = P[far * 3 + 2];
      scx = cx; scy = cy; scz = cz;
      fidx[b * GG + it] = far;
      center[(size_t)(b * GG + it) * 3 + 0] = cx;
      center[(size_t)(b * GG + it) * 3 + 1] = cy;
      center[(size_t)(b * GG + it) * 3 + 2] = cz;
    }
    __syncthreads();
    float cx = scx, cy = scy, cz = scz;
    unsigned long long best = 0;
#pragma unroll
    for (int j = 0; j < 8; j++) {
      float dx = __fsub_rn(x[j], cx);
      float dy = __fsub_rn(y[j], cy);
      float dz = __fsub_rn(z[j], cz);
      float d = __fadd_rn(__fadd_rn(__fmul_rn(dx, dx), __fmul_rn(dy, dy)), __fmul_rn(dz, dz));
      float dm = fminf(dmin[j], d);
      dmin[j] = dm;
      unsigned long long key = ((unsigned long long)__float_as_uint(dm) << 32)
                             | (unsigned)(0xFFFFFFFFu - (unsigned)(tid + 1024 * j));
      best = (key > best) ? key : best;
    }
#pragma unroll
    for (int off = 32; off > 0; off >>= 1) {
      unsigned long long o = __shfl_xor(best, off);
      best = (o > best) ? o : best;
    }
    int lane = tid & 63, wid = tid >> 6;
    if (lane == 0) sred[wid] = best;
    __syncthreads();
    if (tid < 16) {
      unsigned long long v = sred[tid];
#pragma unroll
      for (int off = 8; off > 0; off >>= 1) {
        unsigned long long o = __shfl_xor(v, off);
        v = (o > v) ? o : v;
      }
      if (tid == 0) sfar = (int)(0xFFFFFFFFu - (unsigned)(v & 0xFFFFFFFFu));
    }
    __syncthreads();
    far = sfar;
  }
}

// ---------------------------------------------------------------- KNN (unchanged)
__global__ __launch_bounds__(256) void knn_kernel(const float* __restrict__ pts,
                                                  const float* __restrict__ center,
                                                  int* __restrict__ knn_idx) {
  int bg = blockIdx.x;
  int b = bg >> 9;
  int tid = threadIdx.x;
  __shared__ float dist[NN];
  __shared__ unsigned long long sred[4];
  const float* P = pts + (size_t)b * NN * 3;
  float cx = center[bg * 3 + 0], cy = center[bg * 3 + 1], cz = center[bg * 3 + 2];
  for (int j = 0; j < 32; j++) {
    int p = tid + 256 * j;
    float dx = P[p * 3 + 0] - cx, dy = P[p * 3 + 1] - cy, dz = P[p * 3 + 2] - cz;
    dist[p] = dx * dx + dy * dy + dz * dz;
  }
  __syncthreads();
  for (int r = 0; r < KK; r++) {
    unsigned long long best = 0xFFFFFFFFFFFFFFFFull;
#pragma unroll 8
    for (int j = 0; j < 32; j++) {
      int p = tid + 256 * j;
      unsigned long long key = ((unsigned long long)__float_as_uint(dist[p]) << 32) | (unsigned)p;
      best = (key < best) ? key : best;
    }
#pragma unroll
    for (int off = 32; off > 0; off >>= 1) {
      unsigned long long o = __shfl_xor(best, off);
      best = (o < best) ? o : best;
    }
    int lane = tid & 63, wid = tid >> 6;
    if (lane == 0) sred[wid] = best;
    __syncthreads();
    if (tid < 4) {
      unsigned long long v = sred[tid];
      unsigned long long o = __shfl_xor(v, 1); v = (o < v) ? o : v;
      o = __shfl_xor(v, 2); v = (o < v) ? o : v;
      if (tid == 0) {
        int p = (int)(v & 0xFFFFFFFFu);
        knn_idx[bg * KK + r] = p;
        dist[p] = 3.0e38f;
      }
    }
    __syncthreads();
  }
}

// ---------------------------------------------------------------- convert fp32 -> bf16
__global__ __launch_bounds__(256) void cvt_kernel(const float* __restrict__ s,
                                                  unsigned short* __restrict__ d, int n) {
  int i = (blockIdx.x * 256 + threadIdx.x) * 4;
  if (i + 3 < n) {
    float4 v = *reinterpret_cast<const float4*>(&s[i]);
    d[i + 0] = f2b(v.x); d[i + 1] = f2b(v.y); d[i + 2] = f2b(v.z); d[i + 3] = f2b(v.w);
  }
}

// ---------------------------------------------------------------- transpose-convert: src[K,N] f32 -> dst[N,K] bf16
__global__ __launch_bounds__(256) void tc_kernel(const float* __restrict__ src,
                                                 unsigned short* __restrict__ dst,
                                                 int K, int N) {
  __shared__ float t[32][33];
  int n0 = blockIdx.x * 32, k0 = blockIdx.y * 32;
  int tx = threadIdx.x & 31, ty = threadIdx.x >> 5;  // 32 x 8
#pragma unroll
  for (int i = 0; i < 32; i += 8)
    t[ty + i][tx] = src[(size_t)(k0 + ty + i) * N + n0 + tx];
  __syncthreads();
#pragma unroll
  for (int i = 0; i < 32; i += 8)
    dst[(size_t)(n0 + ty + i) * K + k0 + tx] = f2b(t[tx][ty + i]);
}

// ---------------------------------------------------------------- encoder stage 1a (gather + 6-MAC + bn + relu -> bf16)
__global__ __launch_bounds__(256) void enc1a_kernel(
    const float* __restrict__ pts, const float* __restrict__ colors,
    const int* __restrict__ knn_idx, const float* __restrict__ center,
    const float* __restrict__ w1a, const float* __restrict__ b1a,
    const float* __restrict__ bn1g, const float* __restrict__ bn1b,
    const float* __restrict__ bn1m, const float* __restrict__ bn1v,
    unsigned short* __restrict__ f1, int gbase)
{
  int g = gbase + blockIdx.x;
  int b = g >> 9;
  int tid = threadIdx.x;
  __shared__ float feat[KK][8];
  if (tid < 192) {
    int k = tid / 6, c = tid % 6;
    int p = knn_idx[g * KK + k];
    float v;
    if (c < 3) v = pts[(size_t)(b * NN + p) * 3 + c] - center[g * 3 + c];
    else       v = colors[(size_t)(b * NN + p) * 3 + (c - 3)];
    feat[k][c] = v;
  }
  __syncthreads();
  for (int e = tid; e < KK * 128; e += 256) {
    int k = e >> 7, j = e & 127;
    float s = b1a[j];
#pragma unroll
    for (int c = 0; c < 6; c++) s += feat[k][c] * w1a[j * 6 + c];
    s = (s - bn1m[j]) * rsqrtf(bn1v[j] + 1e-5f) * bn1g[j] + bn1b[j];
    f1[((size_t)blockIdx.x * KK + k) * 128 + j] = f2b(fmaxf(s, 0.f));
  }
}

// ---------------------------------------------------------------- maxpool over 32 points (bf16), C=256
__global__ __launch_bounds__(256) void maxpool_kernel(const unsigned short* __restrict__ in,
                                                      unsigned short* __restrict__ out, int total) {
  int e = blockIdx.x * 256 + threadIdx.x;
  if (e >= total) return;
  int g = e >> 8, c = e & 255;
  const unsigned short* p = in + ((size_t)g * 32) * 256 + c;
  float m = -3e38f;
#pragma unroll 8
  for (int k = 0; k < 32; k++) m = fmaxf(m, b2f(p[k * 256]));
  out[e] = f2b(m);
}

// ---------------------------------------------------------------- bf16 MFMA GEMM
// out[M,N] = epi(A[M,K]bf16 @ W[N,K]bf16^T + bias) (+resid fp32). 128x128 tile, BK=32,
// 4 waves, each 64x64 via 4x4 mfma_f32_16x16x32_bf16 fragments.
// CONCAT: A-operand k<256 reads fg[group(row)][k] (group = row>>5), k>=256 reads A[row][k-256] (stride 256).
// ACT: 0 none, 1 gelu, 2 bn+relu. OUTBF: bf16 vs fp32 out.
template <int ACT, int RESID, int OUTBF, int CONCAT>
__global__ __launch_bounds__(256) void bgemm(
    const unsigned short* __restrict__ A, const unsigned short* __restrict__ fg,
    const unsigned short* __restrict__ W, const float* __restrict__ bias,
    const float* __restrict__ resid, void* __restrict__ outp,
    int M, int N, int K,
    const float* __restrict__ bng, const float* __restrict__ bnb,
    const float* __restrict__ bnm, const float* __restrict__ bnv)
{
  __shared__ unsigned short As[128][40];   // pad 40: uniform 8 dwords/bank on b128 reads
  __shared__ unsigned short Bs[128][40];
  const int tid = threadIdx.x;
  const int tm0 = blockIdx.y * 128, tn0 = blockIdx.x * 128;
  const int w = tid >> 6, l = tid & 63;
  const int wr = (w >> 1) * 64, wc = (w & 1) * 64;
  const int lr = l & 15, lk = l >> 4;

  f32x4 zero4 = {0.f, 0.f, 0.f, 0.f};
  f32x4 acc[4][4];
#pragma unroll
  for (int m = 0; m < 4; m++)
#pragma unroll
    for (int n = 0; n < 4; n++) acc[m][n] = zero4;

  for (int k0 = 0; k0 < K; k0 += 32) {
#pragma unroll
    for (int c = 0; c < 2; c++) {
      int s = tid + c * 256;          // 0..511 : 128 rows x 4 chunks of 8 bf16
      int row = s >> 2, kp = s & 3;
      uint4 va = make_uint4(0u, 0u, 0u, 0u);
      int grow = tm0 + row;
      if (grow < M) {
        if (CONCAT) {
          int kk = k0 + kp * 8;
          const unsigned short* src = (kk < 256)
              ? &fg[((size_t)(grow >> 5)) * 256 + kk]
              : &A[(size_t)grow * 256 + (kk - 256)];
          va = *reinterpret_cast<const uint4*>(src);
        } else {
          va = *reinterpret_cast<const uint4*>(&A[(size_t)grow * K + k0 + kp * 8]);
        }
      }
      *reinterpret_cast<uint4*>(&As[row][kp * 8]) = va;
      uint4 vb = *reinterpret_cast<const uint4*>(&W[(size_t)(tn0 + row) * K + k0 + kp * 8]);
      *reinterpret_cast<uint4*>(&Bs[row][kp * 8]) = vb;
    }
    __syncthreads();
    bf16x8 af[4], bfr[4];
#pragma unroll
    for (int m = 0; m < 4; m++)
      af[m] = *reinterpret_cast<const bf16x8*>(&As[wr + m * 16 + lr][lk * 8]);
#pragma unroll
    for (int n = 0; n < 4; n++)
      bfr[n] = *reinterpret_cast<const bf16x8*>(&Bs[wc + n * 16 + lr][lk * 8]);
#pragma unroll
    for (int m = 0; m < 4; m++)
#pragma unroll
      for (int n = 0; n < 4; n++)
        acc[m][n] = __builtin_amdgcn_mfma_f32_16x16x32_bf16(af[m], bfr[n], acc[m][n], 0, 0, 0);
    __syncthreads();
  }
#pragma unroll
  for (int m = 0; m < 4; m++) {
#pragma unroll
    for (int r = 0; r < 4; r++) {
      int row = tm0 + wr + m * 16 + lk * 4 + r;
      if (row >= M) continue;
#pragma unroll
      for (int n = 0; n < 4; n++) {
        int col = tn0 + wc + n * 16 + lr;
        float v = acc[m][n][r] + bias[col];
        if (ACT == 1) v = gelu_f(v);
        if (ACT == 2) {
          v = (v - bnm[col]) * rsqrtf(bnv[col] + 1e-5f) * bng[col] + bnb[col];
          v = fmaxf(v, 0.f);
        }
        if (RESID) v += resid[(size_t)row * N + col];
        if (OUTBF) ((unsigned short*)outp)[(size_t)row * N + col] = f2b(v);
        else       ((float*)outp)[(size_t)row * N + col] = v;
      }
    }
  }
}

// ---------------------------------------------------------------- fp32 GEMM (kept for pe + final t2e)
template <int TRANSB, int ACT, int RESID>
__global__ __launch_bounds__(256) void gemm_kernel(
    const float* __restrict__ A, const float* __restrict__ W,
    const float* __restrict__ bias, const float* __restrict__ resid,
    float* __restrict__ out, int M, int N, int K)
{
  __shared__ float Asm[16][64];
  __shared__ float Bsm[16][64];
  int tile_n = blockIdx.x * 64, tile_m = blockIdx.y * 64;
  int tid = threadIdx.x;
  int tm = tid >> 4, tn = tid & 15;
  float acc[4][4] = {};
  for (int k0 = 0; k0 < K; k0 += 16) {
    {
      int e = tid * 4;
      int m = e >> 4, k = e & 15;
      int row = tile_m + m;
      float4 v = make_float4(0.f, 0.f, 0.f, 0.f);
      if (row < M) v = *reinterpret_cast<const float4*>(&A[(size_t)row * K + k0 + k]);
      Asm[k + 0][m] = v.x; Asm[k + 1][m] = v.y; Asm[k + 2][m] = v.z; Asm[k + 3][m] = v.w;
    }
    if (TRANSB == 0) {
      int e = tid * 4;
      int n = e & 63, k = e >> 6;
      float4 v = *reinterpret_cast<const float4*>(&W[(size_t)(k0 + k) * N + tile_n + n]);
      *reinterpret_cast<float4*>(&Bsm[k][n]) = v;
    } else {
      int e = tid * 4;
      int k = e & 15, n = e >> 4;
      float4 v = *reinterpret_cast<const float4*>(&W[(size_t)(tile_n + n) * K + k0 + k]);
      Bsm[k + 0][n] = v.x; Bsm[k + 1][n] = v.y; Bsm[k + 2][n] = v.z; Bsm[k + 3][n] = v.w;
    }
    __syncthreads();
#pragma unroll
    for (int kk = 0; kk < 16; kk++) {
      float4 a = *reinterpret_cast<const float4*>(&Asm[kk][tm * 4]);
      float4 wv = *reinterpret_cast<const float4*>(&Bsm[kk][tn * 4]);
      acc[0][0] += a.x * wv.x; acc[0][1] += a.x * wv.y; acc[0][2] += a.x * wv.z; acc[0][3] += a.x * wv.w;
      acc[1][0] += a.y * wv.x; acc[1][1] += a.y * wv.y; acc[1][2] += a.y * wv.z; acc[1][3] += a.y * wv.w;
      acc[2][0] += a.z * wv.x; acc[2][1] += a.z * wv.y; acc[2][2] += a.z * wv.z; acc[2][3] += a.z * wv.w;
      acc[3][0] += a.w * wv.x; acc[3][1] += a.w * wv.y; acc[3][2] += a.w * wv.z; acc[3][3] += a.w * wv.w;
    }
    __syncthreads();
  }
#pragma unroll
  for (int i = 0; i < 4; i++) {
    int row = tile_m + tm * 4 + i;
    if (row >= M) continue;
    int col = tile_n + tn * 4;
    float4 r;
    r.x = acc[i][0] + bias[col + 0];
    r.y = acc[i][1] + bias[col + 1];
    r.z = acc[i][2] + bias[col + 2];
    r.w = acc[i][3] + bias[col + 3];
    if (ACT == 1) { r.x = gelu_f(r.x); r.y = gelu_f(r.y); r.z = gelu_f(r.z); r.w = gelu_f(r.w); }
    if (RESID) {
      float4 rr = *reinterpret_cast<const float4*>(&resid[(size_t)row * N + col]);
      r.x += rr.x; r.y += rr.y; r.z += rr.z; r.w += rr.w;
    }
    *reinterpret_cast<float4*>(&out[(size_t)row * N + col]) = r;
  }
}

// ---------------------------------------------------------------- LayerNorm (templated output dtype)
template <int OUTBF>
__global__ __launch_bounds__(256) void ln_kernel(const float* __restrict__ x,
                                                 const float* __restrict__ g,
                                                 const float* __restrict__ bta,
                                                 void* __restrict__ yv) {
  int r = blockIdx.x;
  int tid = threadIdx.x;
  __shared__ float sred[4];
  __shared__ float smu, srs;
  const float* xr = x + (size_t)r * 768;
  float v0 = xr[tid], v1 = xr[tid + 256], v2 = xr[tid + 512];
  float s = v0 + v1 + v2;
#pragma unroll
  for (int off = 32; off > 0; off >>= 1) s += __shfl_xor(s, off);
  if ((tid & 63) == 0) sred[tid >> 6] = s;
  __syncthreads();
  if (tid < 4) {
    float t = sred[tid];
    t += __shfl_xor(t, 1); t += __shfl_xor(t, 2);
    if (tid == 0) smu = t * (1.f / 768.f);
  }
  __syncthreads();
  float mu = smu;
  float d0 = v0 - mu, d1 = v1 - mu, d2 = v2 - mu;
  float ss = d0 * d0 + d1 * d1 + d2 * d2;
#pragma unroll
  for (int off = 32; off > 0; off >>= 1) ss += __shfl_xor(ss, off);
  if ((tid & 63) == 0) sred[tid >> 6] = ss;
  __syncthreads();
  if (tid < 4) {
    float t = sred[tid];
    t += __shfl_xor(t, 1); t += __shfl_xor(t, 2);
    if (tid == 0) srs = rsqrtf(t * (1.f / 768.f) + 1e-5f);
  }
  __syncthreads();
  float rs = srs;
  float o0 = d0 * rs * g[tid]       + bta[tid];
  float o1 = d1 * rs * g[tid + 256] + bta[tid + 256];
  float o2 = d2 * rs * g[tid + 512] + bta[tid + 512];
  if (OUTBF) {
    unsigned short* yr = (unsigned short*)yv + (size_t)r * 768;
    yr[tid] = f2b(o0); yr[tid + 256] = f2b(o1); yr[tid + 512] = f2b(o2);
  } else {
    float* yr = (float*)yv + (size_t)r * 768;
    yr[tid] = o0; yr[tid + 256] = o1; yr[tid + 512] = o2;
  }
}

// ---------------------------------------------------------------- pos-embed hidden (fp32, unchanged)
__global__ __launch_bounds__(256) void pe_hidden_kernel(const float* __restrict__ center,
                                                        const float* __restrict__ w1,
                                                        const float* __restrict__ b1,
                                                        float* __restrict__ hid) {
  int e = blockIdx.x * 256 + threadIdx.x;
  int r = e >> 7, j = e & 127;
  float cx = center[r * 3 + 0], cy = center[r * 3 + 1], cz = center[r * 3 + 2];
  float s = b1[j] + cx * w1[j * 3 + 0] + cy * w1[j * 3 + 1] + cz * w1[j * 3 + 2];
  hid[e] = gelu_f(s);
}

// ---------------------------------------------------------------- assemble xs (fp32, unchanged)
__global__ __launch_bounds__(256) void assemble_kernel(const float* __restrict__ tp,
                                                       const float* __restrict__ pp,
                                                       const float* __restrict__ cls_tok,
                                                       const float* __restrict__ cls_pos,
                                                       float* __restrict__ xs) {
  int r = blockIdx.x;
  int b = r / SS, t = r % SS;
  int tid = threadIdx.x;
  float* xr = xs + (size_t)r * 768;
  if (t == 0) {
    for (int d = tid; d < 768; d += 256) xr[d] = cls_tok[d] + cls_pos[d];
  } else {
    int g = b * GG + (t - 1);
    for (int d = tid; d < 768; d += 256) xr[d] = tp[(size_t)g * 768 + d] + pp[(size_t)g * 768 + d];
  }
}

// ---------------------------------------------------------------- flash attention (fp32 in, bf16 out)
__global__ __launch_bounds__(256) void flash_kernel(const float* __restrict__ qkv,
                                                    unsigned short* __restrict__ o) {
  int qt = blockIdx.x, h = blockIdx.y, b = blockIdx.z;
  int tid = threadIdx.x;
  int rr = tid >> 2, cg = tid & 3;
  __shared__ float Ks[64][68];
  __shared__ float Vs[64][68];
  __shared__ float Ps[64][68];
  const float scale = 0.125f;
  int qrow = qt * 64 + rr;
  bool qvalid = qrow < SS;
  float q[16];
  {
    const float* qp = qkv + (size_t)(b * SS + (qvalid ? qrow : 0)) * 2304 + h * 64 + cg * 16;
#pragma unroll
    for (int i = 0; i < 16; i += 4) {
      float4 v = *reinterpret_cast<const float4*>(qp + i);
      q[i + 0] = qvalid ? v.x * scale : 0.f;
      q[i + 1] = qvalid ? v.y * scale : 0.f;
      q[i + 2] = qvalid ? v.z * scale : 0.f;
      q[i + 3] = qvalid ? v.w * scale : 0.f;
    }
  }
  float O[16];
#pragma unroll
  for (int i = 0; i < 16; i++) O[i] = 0.f;
  float mrow = -3e38f, lrow = 0.f;
  for (int kc = 0; kc < 9; kc++) {
    int kbase = kc * 64;
    for (int e = tid; e < 64 * 64; e += 256) {
      int krow = e >> 6, d = e & 63;
      int gk = kbase + krow;
      float kv = 0.f, vv = 0.f;
      if (gk < SS) {
        const float* pk = qkv + (size_t)(b * SS + gk) * 2304 + 768 + h * 64 + d;
        kv = *pk; vv = pk[768];
      }
      Ks[krow][d] = kv; Vs[krow][d] = vv;
    }
    __syncthreads();
    float svals[16];
    float mc = -3e38f;
    for (int kk = 0; kk < 64; kk++) {
      const float* kr = &Ks[kk][cg * 16];
      float p = 0.f;
#pragma unroll
      for (int i = 0; i < 16; i++) p += q[i] * kr[i];
      p += __shfl_xor(p, 1);
      p += __shfl_xor(p, 2);
      float s = (kbase + kk < SS) ? p : -3e38f;
      if ((kk & 3) == cg) svals[kk >> 2] = s;
      mc = fmaxf(mc, s);
    }
    float mnew = fmaxf(mrow, mc);
    float alpha = __expf(mrow - mnew);
    float lsum = 0.f;
#pragma unroll
    for (int jj = 0; jj < 16; jj++) {
      float pexp = __expf(svals[jj] - mnew);
      lsum += pexp;
      Ps[rr][jj * 4 + cg] = pexp;
    }
    lsum += __shfl_xor(lsum, 1);
    lsum += __shfl_xor(lsum, 2);
    lrow = lrow * alpha + lsum;
#pragma unroll
    for (int i = 0; i < 16; i++) O[i] *= alpha;
    mrow = mnew;
    __syncthreads();
#pragma unroll 4
    for (int kk = 0; kk < 64; kk++) {
      float pw = Ps[rr][kk];
      const float* vr = &Vs[kk][cg * 16];
#pragma unroll
      for (int i = 0; i < 16; i++) O[i] += pw * vr[i];
    }
    __syncthreads();
  }
  if (qvalid) {
    float inv = 1.f / lrow;
    unsigned short* op = o + (size_t)(b * SS + qrow) * 768 + h * 64 + cg * 16;
#pragma unroll
    for (int i = 0; i < 16; i++) op[i] = f2b(O[i] * inv);
  }
}

// ---------------------------------------------------------------- launch
extern "C" void kernel_launch(void* const* d_in, const int* in_sizes, int n_in,
                              void* d_out, int out_size, void* d_ws, size_t ws_size,
                              hipStream_t stream) {
  const float* pts    = (const float*)d_in[0];
  const float* colors = (const float*)d_in[1];
  const float* w1a    = (const float*)d_in[2];
  const float* b1a    = (const float*)d_in[3];
  const float* bn1g   = (const float*)d_in[4];
  const float* bn1b   = (const float*)d_in[5];
  const float* bn1m   = (const float*)d_in[6];
  const float* bn1v   = (const float*)d_in[7];
  const float* w1b    = (const float*)d_in[8];
  const float* b1b    = (const float*)d_in[9];
  const float* w2a    = (const float*)d_in[10];
  const float* b2a    = (const float*)d_in[11];
  const float* bn2g   = (const float*)d_in[12];
  const float* bn2b   = (const float*)d_in[13];
  const float* bn2m   = (const float*)d_in[14];
  const float* bn2v   = (const float*)d_in[15];
  const float* w2b    = (const float*)d_in[16];
  const float* b2b    = (const float*)d_in[17];
  const float* e2t_w  = (const float*)d_in[18];
  const float* e2t_b  = (const float*)d_in[19];
  const float* cls_token = (const float*)d_in[20];
  const float* cls_pos   = (const float*)d_in[21];
  const float* pe_w1  = (const float*)d_in[22];
  const float* pe_b1  = (const float*)d_in[23];
  const float* pe_w2  = (const float*)d_in[24];
  const float* pe_b2  = (const float*)d_in[25];
  const float* ln1_g  = (const float*)d_in[26];
  const float* ln1_b  = (const float*)d_in[27];
  const float* qkv_w  = (const float*)d_in[28];
  const float* qkv_b  = (const float*)d_in[29];
  const float* proj_w = (const float*)d_in[30];
  const float* proj_b = (const float*)d_in[31];
  const float* ln2_g  = (const float*)d_in[32];
  const float* ln2_b  = (const float*)d_in[33];
  const float* mlp_w1 = (const float*)d_in[34];
  const float* mlp_b1 = (const float*)d_in[35];
  const float* mlp_w2 = (const float*)d_in[36];
  const float* mlp_b2 = (const float*)d_in[37];
  const float* fcn_g  = (const float*)d_in[38];
  const float* fcn_b  = (const float*)d_in[39];
  const float* t2e_w  = (const float*)d_in[40];
  const float* t2e_b  = (const float*)d_in[41];

  if (ws_size < (size_t)67174400) return;  // insufficient scratch -> fail visibly

  char* ws = (char*)d_ws;
  int*            fidx   = (int*)(ws + 0);
  float*          center = (float*)(ws + 8192);
  int*            knn    = (int*)(ws + 32768);
  unsigned short* tok    = (unsigned short*)(ws + 294912);    // [2048,256] bf16
  float*          xs     = (float*)(ws + 1343488);            // [2052,768] f32
  unsigned short* hbuf   = (unsigned short*)(ws + 7647232);   // [2052,768] bf16
  float*          fbuf   = (float*)(ws + 10799104);           // [2052,768] f32
  char*           WT     = ws + 17102848;                     // weight arena (15.4 MB)
  unsigned short* qkv_wt = (unsigned short*)(WT + 0);         // [2304,768]
  unsigned short* proj_wt= (unsigned short*)(WT + 3538944);   // [768,768]
  unsigned short* w1t    = (unsigned short*)(WT + 4718592);   // [3072,768]
  unsigned short* w2t    = (unsigned short*)(WT + 9437184);   // [768,3072]
  unsigned short* w1bb   = (unsigned short*)(WT + 14155776);  // [256,128]
  unsigned short* w2ab   = (unsigned short*)(WT + 14221312);  // [512,512]
  unsigned short* w2bb   = (unsigned short*)(WT + 14745600);  // [256,512]
  unsigned short* e2tb   = (unsigned short*)(WT + 15007744);  // [768,256]
  char*           BA     = ws + 32503808;                     // big arena (34.7 MB)
  // encoder chunk phase
  unsigned short* f1   = (unsigned short*)(BA + 0);           // [16384,128]
  unsigned short* f2   = (unsigned short*)(BA + 4194304);     // [16384,256]
  unsigned short* fg   = (unsigned short*)(BA + 12582912);    // [512,256]
  unsigned short* f3   = (unsigned short*)(BA + 12845056);    // [16384,512]
  unsigned short* f4   = (unsigned short*)(BA + 0);           // [16384,256] (over f1/f2, dead)
  // pre-transformer phase
  float*          tp   = (float*)(BA + 0);                    // [2048,768] f32
  float*          pp   = (float*)(BA + 6291456);              // [2048,768] f32
  float*          hid  = (float*)(BA + 12582912);             // [2048,128] f32
  // transformer phase
  float*          qkvb = (float*)(BA + 0);                    // [2052,2304] f32
  unsigned short* obuf = (unsigned short*)(BA + 18911232);    // [2052,768] bf16
  unsigned short* mh   = (unsigned short*)(BA + 22063104);    // [2052,3072] bf16

  // encoder weights -> bf16 (once)
  cvt_kernel<<<32, 256, 0, stream>>>(w1b, w1bb, 32768);
  cvt_kernel<<<256, 256, 0, stream>>>(w2a, w2ab, 262144);
  cvt_kernel<<<128, 256, 0, stream>>>(w2b, w2bb, 131072);
  cvt_kernel<<<192, 256, 0, stream>>>(e2t_w, e2tb, 196608);

  fps_kernel<<<BB, 1024, 0, stream>>>(pts, fidx, center);
  knn_kernel<<<BB * GG, 256, 0, stream>>>(pts, center, knn);

  // encoder: 4 chunks of 512 groups (16384 points)
  for (int c = 0; c < 4; c++) {
    int gbase = c * 512;
    enc1a_kernel<<<512, 256, 0, stream>>>(pts, colors, knn, center,
        w1a, b1a, bn1g, bn1b, bn1m, bn1v, f1, gbase);
    bgemm<0, 0, 1, 0><<<dim3(2, 128), 256, 0, stream>>>(f1, nullptr, w1bb, b1b,
        nullptr, f2, 16384, 256, 128, nullptr, nullptr, nullptr, nullptr);
    maxpool_kernel<<<512, 256, 0, stream>>>(f2, fg, 512 * 256);
    bgemm<2, 0, 1, 1><<<dim3(4, 128), 256, 0, stream>>>(f2, fg, w2ab, b2a,
        nullptr, f3, 16384, 512, 512, bn2g, bn2b, bn2m, bn2v);
    bgemm<0, 0, 1, 0><<<dim3(2, 128), 256, 0, stream>>>(f3, nullptr, w2bb, b2b,
        nullptr, f4, 16384, 256, 512, nullptr, nullptr, nullptr, nullptr);
    maxpool_kernel<<<512, 256, 0, stream>>>(f4, tok + (size_t)gbase * 256, 512 * 256);
  }

  // tokens/pos -> xs
  bgemm<0, 0, 0, 0><<<dim3(6, 16), 256, 0, stream>>>(tok, nullptr, e2tb, e2t_b,
      nullptr, tp, 2048, 768, 256, nullptr, nullptr, nullptr, nullptr);
  pe_hidden_kernel<<<1024, 256, 0, stream>>>(center, pe_w1, pe_b1, hid);
  gemm_kernel<1, 0, 0><<<dim3(12, 32), 256, 0, stream>>>(hid, pe_w2, pe_b2, nullptr, pp, 2048, 768, 128);
  assemble_kernel<<<BB * SS, 256, 0, stream>>>(tp, pp, cls_token, cls_pos, xs);

  for (int i = 0; i < 4; i++) {
    // layer weights -> bf16 transposed ([N,K])
    tc_kernel<<<dim3(72, 24), 256, 0, stream>>>(qkv_w + (size_t)i * 768 * 2304, qkv_wt, 768, 2304);
    tc_kernel<<<dim3(24, 24), 256, 0, stream>>>(proj_w + (size_t)i * 768 * 768, proj_wt, 768, 768);
    tc_kernel<<<dim3(96, 24), 256, 0, stream>>>(mlp_w1 + (size_t)i * 768 * 3072, w1t, 768, 3072);
    tc_kernel<<<dim3(24, 96), 256, 0, stream>>>(mlp_w2 + (size_t)i * 3072 * 768, w2t, 3072, 768);

    ln_kernel<1><<<BB * SS, 256, 0, stream>>>(xs, ln1_g + i * 768, ln1_b + i * 768, hbuf);
    bgemm<0, 0, 0, 0><<<dim3(18, 17), 256, 0, stream>>>(hbuf, nullptr, qkv_wt,
        qkv_b + i * 2304, nullptr, qkvb, 2052, 2304, 768, nullptr, nullptr, nullptr, nullptr);
    flash_kernel<<<dim3(9, 12, 4), 256, 0, stream>>>(qkvb, obuf);
    bgemm<0, 1, 0, 0><<<dim3(6, 17), 256, 0, stream>>>(obuf, nullptr, proj_wt,
        proj_b + i * 768, xs, xs, 2052, 768, 768, nullptr, nullptr, nullptr, nullptr);
    ln_kernel<1><<<BB * SS, 256, 0, stream>>>(xs, ln2_g + i * 768, ln2_b + i * 768, hbuf);
    bgemm<1, 0, 1, 0><<<dim3(24, 17), 256, 0, stream>>>(hbuf, nullptr, w1t,
        mlp_b1 + i * 3072, nullptr, mh, 2052, 3072, 768, nullptr, nullptr, nullptr, nullptr);
    bgemm<0, 1, 0, 0><<<dim3(6, 17), 256, 0, stream>>>(mh, nullptr, w2t,
        mlp_b2 + i * 768, xs, xs, 2052, 768, 3072, nullptr, nullptr, nullptr, nullptr);
  }

  // final: fully fp32 path
  ln_kernel<0><<<BB * SS, 256, 0, stream>>>(xs, fcn_g, fcn_b, fbuf);
  gemm_kernel<1, 0, 0><<<dim3(12, 33), 256, 0, stream>>>(fbuf, t2e_w, t2e_b, nullptr,
      (float*)d_out, 2052, 768, 768);
}

// Round 7
// 2735.959 us; speedup vs baseline: 2.8666x; 1.0898x over previous
//
#include <hip/hip_runtime.h>
#include <math.h>

#define BB 4
#define NN 8192
#define GG 512
#define KK 32
#define DD 768
#define SS 513
#define HH 12

typedef __attribute__((ext_vector_type(8))) short bf16x8;
typedef __attribute__((ext_vector_type(4))) float f32x4;

__device__ __forceinline__ float gelu_f(float x) {
  return 0.5f * x * (1.f + erff(x * 0.70710678118654752f));
}
__device__ __forceinline__ unsigned short f2b(float f) {
  unsigned u = __float_as_uint(f);
  u = (u + 0x7FFFu + ((u >> 16) & 1u)) >> 16;
  return (unsigned short)u;
}
__device__ __forceinline__ float b2f(unsigned short h) {
  return __uint_as_float(((unsigned)h) << 16);
}

// 64-lane reductions via DPP (VALU-only, no LDS latency).
__device__ __forceinline__ unsigned wave_max_u32(unsigned v) {
  unsigned t;
  t = (unsigned)__builtin_amdgcn_update_dpp(0, (int)v, 0x111, 0xf, 0xf, false); v = t > v ? t : v;
  t = (unsigned)__builtin_amdgcn_update_dpp(0, (int)v, 0x112, 0xf, 0xf, false); v = t > v ? t : v;
  t = (unsigned)__builtin_amdgcn_update_dpp(0, (int)v, 0x114, 0xf, 0xf, false); v = t > v ? t : v;
  t = (unsigned)__builtin_amdgcn_update_dpp(0, (int)v, 0x118, 0xf, 0xf, false); v = t > v ? t : v;
  t = (unsigned)__builtin_amdgcn_update_dpp(0, (int)v, 0x142, 0xf, 0xf, false); v = t > v ? t : v;
  t = (unsigned)__builtin_amdgcn_update_dpp(0, (int)v, 0x143, 0xf, 0xf, false); v = t > v ? t : v;
  return (unsigned)__builtin_amdgcn_readlane((int)v, 63);
}
__device__ __forceinline__ unsigned wave_min_u32(unsigned v) {
  unsigned t;
  t = (unsigned)__builtin_amdgcn_update_dpp(0x7FFFFFFF, (int)v, 0x111, 0xf, 0xf, false); v = t < v ? t : v;
  t = (unsigned)__builtin_amdgcn_update_dpp(0x7FFFFFFF, (int)v, 0x112, 0xf, 0xf, false); v = t < v ? t : v;
  t = (unsigned)__builtin_amdgcn_update_dpp(0x7FFFFFFF, (int)v, 0x114, 0xf, 0xf, false); v = t < v ? t : v;
  t = (unsigned)__builtin_amdgcn_update_dpp(0x7FFFFFFF, (int)v, 0x118, 0xf, 0xf, false); v = t < v ? t : v;
  t = (unsigned)__builtin_amdgcn_update_dpp(0x7FFFFFFF, (int)v, 0x142, 0xf, 0xf, false); v = t < v ? t : v;
  t = (unsigned)__builtin_amdgcn_update_dpp(0x7FFFFFFF, (int)v, 0x143, 0xf, 0xf, false); v = t < v ? t : v;
  return (unsigned)__builtin_amdgcn_readlane((int)v, 63);
}

// ---------------------------------------------------------------- FPS
// One block per batch, 512 threads x 16 points. Latency-optimized:
// winner-writes-center (no global read on critical path), DPP wave reduce,
// one LDS u64 atomicMax across 8 wave winners, 2 barriers/iter.
// Exactness: __f*_rn distance (no FMA), strict-> keeps lowest idx in-thread,
// idx-min among value ties cross-thread (ref argmax picks first max).
__global__ __launch_bounds__(512) void fps_kernel(const float* __restrict__ pts,
                                                  int* __restrict__ fidx,
                                                  float* __restrict__ center) {
  int b = blockIdx.x;
  int tid = threadIdx.x;
  const float* P = pts + (size_t)b * NN * 3;
  float x[16], y[16], z[16], dmin[16];
#pragma unroll
  for (int j = 0; j < 16; j++) {
    int p = tid + 512 * j;
    x[j] = P[p * 3 + 0]; y[j] = P[p * 3 + 1]; z[j] = P[p * 3 + 2];
    dmin[j] = 1e10f;
  }
  __shared__ unsigned long long sbest;
  __shared__ float scx, scy, scz;
  if (tid == 0) {
    sbest = 0ull;
    scx = x[0]; scy = y[0]; scz = z[0];
    fidx[b * GG] = 0;
    center[(size_t)(b * GG) * 3 + 0] = x[0];
    center[(size_t)(b * GG) * 3 + 1] = y[0];
    center[(size_t)(b * GG) * 3 + 2] = z[0];
  }
  __syncthreads();
  for (int it = 0; it < GG - 1; it++) {
    float cx = scx, cy = scy, cz = scz;
    unsigned bv = 0u, bi = 0x7FFFFFFFu;
    int bj = 0;
#pragma unroll
    for (int j = 0; j < 16; j++) {
      float dx = __fsub_rn(x[j], cx);
      float dy = __fsub_rn(y[j], cy);
      float dz = __fsub_rn(z[j], cz);
      float d = __fadd_rn(__fadd_rn(__fmul_rn(dx, dx), __fmul_rn(dy, dy)), __fmul_rn(dz, dz));
      float dm = fminf(dmin[j], d);
      dmin[j] = dm;
      unsigned db = __float_as_uint(dm);   // dm >= 0 -> uint order == float order
      if (db > bv) { bv = db; bi = (unsigned)(tid + 512 * j); bj = j; }
    }
    unsigned wmax = wave_max_u32(bv);
    unsigned cand = (bv == wmax) ? bi : 0x7FFFFFFFu;
    unsigned widx = wave_min_u32(cand);
    bool wave_winner = (bv == wmax) && (bi == widx);
    unsigned long long mykey = ((unsigned long long)wmax << 32) | (unsigned long long)(0xFFFFFFFFu - widx);
    if (wave_winner) atomicMax(&sbest, mykey);
    __syncthreads();
    if (wave_winner) {
      if (sbest == mykey) {   // global winner (keys unique: idx embedded)
        scx = x[bj]; scy = y[bj]; scz = z[bj];
        fidx[b * GG + it + 1] = (int)bi;
        center[(size_t)(b * GG + it + 1) * 3 + 0] = x[bj];
        center[(size_t)(b * GG + it + 1) * 3 + 1] = y[bj];
        center[(size_t)(b * GG + it + 1) * 3 + 2] = z[bj];
        sbest = 0ull;
      }
    }
    __syncthreads();
  }
}

// ---------------------------------------------------------------- KNN (unchanged)
__global__ __launch_bounds__(256) void knn_kernel(const float* __restrict__ pts,
                                                  const float* __restrict__ center,
                                                  int* __restrict__ knn_idx) {
  int bg = blockIdx.x;
  int b = bg >> 9;
  int tid = threadIdx.x;
  __shared__ float dist[NN];
  __shared__ unsigned long long sred[4];
  const float* P = pts + (size_t)b * NN * 3;
  float cx = center[bg * 3 + 0], cy = center[bg * 3 + 1], cz = center[bg * 3 + 2];
  for (int j = 0; j < 32; j++) {
    int p = tid + 256 * j;
    float dx = P[p * 3 + 0] - cx, dy = P[p * 3 + 1] - cy, dz = P[p * 3 + 2] - cz;
    dist[p] = dx * dx + dy * dy + dz * dz;
  }
  __syncthreads();
  for (int r = 0; r < KK; r++) {
    unsigned long long best = 0xFFFFFFFFFFFFFFFFull;
#pragma unroll 8
    for (int j = 0; j < 32; j++) {
      int p = tid + 256 * j;
      unsigned long long key = ((unsigned long long)__float_as_uint(dist[p]) << 32) | (unsigned)p;
      best = (key < best) ? key : best;
    }
#pragma unroll
    for (int off = 32; off > 0; off >>= 1) {
      unsigned long long o = __shfl_xor(best, off);
      best = (o < best) ? o : best;
    }
    int lane = tid & 63, wid = tid >> 6;
    if (lane == 0) sred[wid] = best;
    __syncthreads();
    if (tid < 4) {
      unsigned long long v = sred[tid];
      unsigned long long o = __shfl_xor(v, 1); v = (o < v) ? o : v;
      o = __shfl_xor(v, 2); v = (o < v) ? o : v;
      if (tid == 0) {
        int p = (int)(v & 0xFFFFFFFFu);
        knn_idx[bg * KK + r] = p;
        dist[p] = 3.0e38f;
      }
    }
    __syncthreads();
  }
}

// ---------------------------------------------------------------- convert fp32 -> bf16
__global__ __launch_bounds__(256) void cvt_kernel(const float* __restrict__ s,
                                                  unsigned short* __restrict__ d, int n) {
  int i = (blockIdx.x * 256 + threadIdx.x) * 4;
  if (i + 3 < n) {
    float4 v = *reinterpret_cast<const float4*>(&s[i]);
    d[i + 0] = f2b(v.x); d[i + 1] = f2b(v.y); d[i + 2] = f2b(v.z); d[i + 3] = f2b(v.w);
  }
}

// ---------------------------------------------------------------- transpose-convert: src[K,N] f32 -> dst[N,K] bf16
__global__ __launch_bounds__(256) void tc_kernel(const float* __restrict__ src,
                                                 unsigned short* __restrict__ dst,
                                                 int K, int N) {
  __shared__ float t[32][33];
  int n0 = blockIdx.x * 32, k0 = blockIdx.y * 32;
  int tx = threadIdx.x & 31, ty = threadIdx.x >> 5;  // 32 x 8
#pragma unroll
  for (int i = 0; i < 32; i += 8)
    t[ty + i][tx] = src[(size_t)(k0 + ty + i) * N + n0 + tx];
  __syncthreads();
#pragma unroll
  for (int i = 0; i < 32; i += 8)
    dst[(size_t)(n0 + ty + i) * K + k0 + tx] = f2b(t[tx][ty + i]);
}

// ---------------------------------------------------------------- encoder stage 1a
__global__ __launch_bounds__(256) void enc1a_kernel(
    const float* __restrict__ pts, const float* __restrict__ colors,
    const int* __restrict__ knn_idx, const float* __restrict__ center,
    const float* __restrict__ w1a, const float* __restrict__ b1a,
    const float* __restrict__ bn1g, const float* __restrict__ bn1b,
    const float* __restrict__ bn1m, const float* __restrict__ bn1v,
    unsigned short* __restrict__ f1, int gbase)
{
  int g = gbase + blockIdx.x;
  int b = g >> 9;
  int tid = threadIdx.x;
  __shared__ float feat[KK][8];
  if (tid < 192) {
    int k = tid / 6, c = tid % 6;
    int p = knn_idx[g * KK + k];
    float v;
    if (c < 3) v = pts[(size_t)(b * NN + p) * 3 + c] - center[g * 3 + c];
    else       v = colors[(size_t)(b * NN + p) * 3 + (c - 3)];
    feat[k][c] = v;
  }
  __syncthreads();
  for (int e = tid; e < KK * 128; e += 256) {
    int k = e >> 7, j = e & 127;
    float s = b1a[j];
#pragma unroll
    for (int c = 0; c < 6; c++) s += feat[k][c] * w1a[j * 6 + c];
    s = (s - bn1m[j]) * rsqrtf(bn1v[j] + 1e-5f) * bn1g[j] + bn1b[j];
    f1[((size_t)blockIdx.x * KK + k) * 128 + j] = f2b(fmaxf(s, 0.f));
  }
}

// ---------------------------------------------------------------- maxpool over 32 points (bf16), C=256
__global__ __launch_bounds__(256) void maxpool_kernel(const unsigned short* __restrict__ in,
                                                      unsigned short* __restrict__ out, int total) {
  int e = blockIdx.x * 256 + threadIdx.x;
  if (e >= total) return;
  int g = e >> 8, c = e & 255;
  const unsigned short* p = in + ((size_t)g * 32) * 256 + c;
  float m = -3e38f;
#pragma unroll 8
  for (int k = 0; k < 32; k++) m = fmaxf(m, b2f(p[k * 256]));
  out[e] = f2b(m);
}

// ---------------------------------------------------------------- bf16 MFMA GEMM
template <int ACT, int RESID, int OUTBF, int CONCAT>
__global__ __launch_bounds__(256) void bgemm(
    const unsigned short* __restrict__ A, const unsigned short* __restrict__ fg,
    const unsigned short* __restrict__ W, const float* __restrict__ bias,
    const float* __restrict__ resid, void* __restrict__ outp,
    int M, int N, int K,
    const float* __restrict__ bng, const float* __restrict__ bnb,
    const float* __restrict__ bnm, const float* __restrict__ bnv)
{
  __shared__ unsigned short As[128][40];
  __shared__ unsigned short Bs[128][40];
  const int tid = threadIdx.x;
  const int tm0 = blockIdx.y * 128, tn0 = blockIdx.x * 128;
  const int w = tid >> 6, l = tid & 63;
  const int wr = (w >> 1) * 64, wc = (w & 1) * 64;
  const int lr = l & 15, lk = l >> 4;

  f32x4 zero4 = {0.f, 0.f, 0.f, 0.f};
  f32x4 acc[4][4];
#pragma unroll
  for (int m = 0; m < 4; m++)
#pragma unroll
    for (int n = 0; n < 4; n++) acc[m][n] = zero4;

  for (int k0 = 0; k0 < K; k0 += 32) {
#pragma unroll
    for (int c = 0; c < 2; c++) {
      int s = tid + c * 256;
      int row = s >> 2, kp = s & 3;
      uint4 va = make_uint4(0u, 0u, 0u, 0u);
      int grow = tm0 + row;
      if (grow < M) {
        if (CONCAT) {
          int kk = k0 + kp * 8;
          const unsigned short* src = (kk < 256)
              ? &fg[((size_t)(grow >> 5)) * 256 + kk]
              : &A[(size_t)grow * 256 + (kk - 256)];
          va = *reinterpret_cast<const uint4*>(src);
        } else {
          va = *reinterpret_cast<const uint4*>(&A[(size_t)grow * K + k0 + kp * 8]);
        }
      }
      *reinterpret_cast<uint4*>(&As[row][kp * 8]) = va;
      uint4 vb = *reinterpret_cast<const uint4*>(&W[(size_t)(tn0 + row) * K + k0 + kp * 8]);
      *reinterpret_cast<uint4*>(&Bs[row][kp * 8]) = vb;
    }
    __syncthreads();
    bf16x8 af[4], bfr[4];
#pragma unroll
    for (int m = 0; m < 4; m++)
      af[m] = *reinterpret_cast<const bf16x8*>(&As[wr + m * 16 + lr][lk * 8]);
#pragma unroll
    for (int n = 0; n < 4; n++)
      bfr[n] = *reinterpret_cast<const bf16x8*>(&Bs[wc + n * 16 + lr][lk * 8]);
#pragma unroll
    for (int m = 0; m < 4; m++)
#pragma unroll
      for (int n = 0; n < 4; n++)
        acc[m][n] = __builtin_amdgcn_mfma_f32_16x16x32_bf16(af[m], bfr[n], acc[m][n], 0, 0, 0);
    __syncthreads();
  }
#pragma unroll
  for (int m = 0; m < 4; m++) {
#pragma unroll
    for (int r = 0; r < 4; r++) {
      int row = tm0 + wr + m * 16 + lk * 4 + r;
      if (row >= M) continue;
#pragma unroll
      for (int n = 0; n < 4; n++) {
        int col = tn0 + wc + n * 16 + lr;
        float v = acc[m][n][r] + bias[col];
        if (ACT == 1) v = gelu_f(v);
        if (ACT == 2) {
          v = (v - bnm[col]) * rsqrtf(bnv[col] + 1e-5f) * bng[col] + bnb[col];
          v = fmaxf(v, 0.f);
        }
        if (RESID) v += resid[(size_t)row * N + col];
        if (OUTBF) ((unsigned short*)outp)[(size_t)row * N + col] = f2b(v);
        else       ((float*)outp)[(size_t)row * N + col] = v;
      }
    }
  }
}

// ---------------------------------------------------------------- fp32 GEMM (pe + final t2e)
template <int TRANSB, int ACT, int RESID>
__global__ __launch_bounds__(256) void gemm_kernel(
    const float* __restrict__ A, const float* __restrict__ W,
    const float* __restrict__ bias, const float* __restrict__ resid,
    float* __restrict__ out, int M, int N, int K)
{
  __shared__ float Asm[16][64];
  __shared__ float Bsm[16][64];
  int tile_n = blockIdx.x * 64, tile_m = blockIdx.y * 64;
  int tid = threadIdx.x;
  int tm = tid >> 4, tn = tid & 15;
  float acc[4][4] = {};
  for (int k0 = 0; k0 < K; k0 += 16) {
    {
      int e = tid * 4;
      int m = e >> 4, k = e & 15;
      int row = tile_m + m;
      float4 v = make_float4(0.f, 0.f, 0.f, 0.f);
      if (row < M) v = *reinterpret_cast<const float4*>(&A[(size_t)row * K + k0 + k]);
      Asm[k + 0][m] = v.x; Asm[k + 1][m] = v.y; Asm[k + 2][m] = v.z; Asm[k + 3][m] = v.w;
    }
    if (TRANSB == 0) {
      int e = tid * 4;
      int n = e & 63, k = e >> 6;
      float4 v = *reinterpret_cast<const float4*>(&W[(size_t)(k0 + k) * N + tile_n + n]);
      *reinterpret_cast<float4*>(&Bsm[k][n]) = v;
    } else {
      int e = tid * 4;
      int k = e & 15, n = e >> 4;
      float4 v = *reinterpret_cast<const float4*>(&W[(size_t)(tile_n + n) * K + k0 + k]);
      Bsm[k + 0][n] = v.x; Bsm[k + 1][n] = v.y; Bsm[k + 2][n] = v.z; Bsm[k + 3][n] = v.w;
    }
    __syncthreads();
#pragma unroll
    for (int kk = 0; kk < 16; kk++) {
      float4 a = *reinterpret_cast<const float4*>(&Asm[kk][tm * 4]);
      float4 wv = *reinterpret_cast<const float4*>(&Bsm[kk][tn * 4]);
      acc[0][0] += a.x * wv.x; acc[0][1] += a.x * wv.y; acc[0][2] += a.x * wv.z; acc[0][3] += a.x * wv.w;
      acc[1][0] += a.y * wv.x; acc[1][1] += a.y * wv.y; acc[1][2] += a.y * wv.z; acc[1][3] += a.y * wv.w;
      acc[2][0] += a.z * wv.x; acc[2][1] += a.z * wv.y; acc[2][2] += a.z * wv.z; acc[2][3] += a.z * wv.w;
      acc[3][0] += a.w * wv.x; acc[3][1] += a.w * wv.y; acc[3][2] += a.w * wv.z; acc[3][3] += a.w * wv.w;
    }
    __syncthreads();
  }
#pragma unroll
  for (int i = 0; i < 4; i++) {
    int row = tile_m + tm * 4 + i;
    if (row >= M) continue;
    int col = tile_n + tn * 4;
    float4 r;
    r.x = acc[i][0] + bias[col + 0];
    r.y = acc[i][1] + bias[col + 1];
    r.z = acc[i][2] + bias[col + 2];
    r.w = acc[i][3] + bias[col + 3];
    if (ACT == 1) { r.x = gelu_f(r.x); r.y = gelu_f(r.y); r.z = gelu_f(r.z); r.w = gelu_f(r.w); }
    if (RESID) {
      float4 rr = *reinterpret_cast<const float4*>(&resid[(size_t)row * N + col]);
      r.x += rr.x; r.y += rr.y; r.z += rr.z; r.w += rr.w;
    }
    *reinterpret_cast<float4*>(&out[(size_t)row * N + col]) = r;
  }
}

// ---------------------------------------------------------------- LayerNorm
template <int OUTBF>
__global__ __launch_bounds__(256) void ln_kernel(const float* __restrict__ x,
                                                 const float* __restrict__ g,
                                                 const float* __restrict__ bta,
                                                 void* __restrict__ yv) {
  int r = blockIdx.x;
  int tid = threadIdx.x;
  __shared__ float sred[4];
  __shared__ float smu, srs;
  const float* xr = x + (size_t)r * 768;
  float v0 = xr[tid], v1 = xr[tid + 256], v2 = xr[tid + 512];
  float s = v0 + v1 + v2;
#pragma unroll
  for (int off = 32; off > 0; off >>= 1) s += __shfl_xor(s, off);
  if ((tid & 63) == 0) sred[tid >> 6] = s;
  __syncthreads();
  if (tid < 4) {
    float t = sred[tid];
    t += __shfl_xor(t, 1); t += __shfl_xor(t, 2);
    if (tid == 0) smu = t * (1.f / 768.f);
  }
  __syncthreads();
  float mu = smu;
  float d0 = v0 - mu, d1 = v1 - mu, d2 = v2 - mu;
  float ss = d0 * d0 + d1 * d1 + d2 * d2;
#pragma unroll
  for (int off = 32; off > 0; off >>= 1) ss += __shfl_xor(ss, off);
  if ((tid & 63) == 0) sred[tid >> 6] = ss;
  __syncthreads();
  if (tid < 4) {
    float t = sred[tid];
    t += __shfl_xor(t, 1); t += __shfl_xor(t, 2);
    if (tid == 0) srs = rsqrtf(t * (1.f / 768.f) + 1e-5f);
  }
  __syncthreads();
  float rs = srs;
  float o0 = d0 * rs * g[tid]       + bta[tid];
  float o1 = d1 * rs * g[tid + 256] + bta[tid + 256];
  float o2 = d2 * rs * g[tid + 512] + bta[tid + 512];
  if (OUTBF) {
    unsigned short* yr = (unsigned short*)yv + (size_t)r * 768;
    yr[tid] = f2b(o0); yr[tid + 256] = f2b(o1); yr[tid + 512] = f2b(o2);
  } else {
    float* yr = (float*)yv + (size_t)r * 768;
    yr[tid] = o0; yr[tid + 256] = o1; yr[tid + 512] = o2;
  }
}

// ---------------------------------------------------------------- pos-embed hidden
__global__ __launch_bounds__(256) void pe_hidden_kernel(const float* __restrict__ center,
                                                        const float* __restrict__ w1,
                                                        const float* __restrict__ b1,
                                                        float* __restrict__ hid) {
  int e = blockIdx.x * 256 + threadIdx.x;
  int r = e >> 7, j = e & 127;
  float cx = center[r * 3 + 0], cy = center[r * 3 + 1], cz = center[r * 3 + 2];
  float s = b1[j] + cx * w1[j * 3 + 0] + cy * w1[j * 3 + 1] + cz * w1[j * 3 + 2];
  hid[e] = gelu_f(s);
}

// ---------------------------------------------------------------- assemble xs
__global__ __launch_bounds__(256) void assemble_kernel(const float* __restrict__ tp,
                                                       const float* __restrict__ pp,
                                                       const float* __restrict__ cls_tok,
                                                       const float* __restrict__ cls_pos,
                                                       float* __restrict__ xs) {
  int r = blockIdx.x;
  int b = r / SS, t = r % SS;
  int tid = threadIdx.x;
  float* xr = xs + (size_t)r * 768;
  if (t == 0) {
    for (int d = tid; d < 768; d += 256) xr[d] = cls_tok[d] + cls_pos[d];
  } else {
    int g = b * GG + (t - 1);
    for (int d = tid; d < 768; d += 256) xr[d] = tp[(size_t)g * 768 + d] + pp[(size_t)g * 768 + d];
  }
}

// ---------------------------------------------------------------- flash attention (fp32 in, bf16 out)
// Full q[64] in registers; each thread computes complete dots for 16 keys
// (kk = 4*jj+cg, conflict-free K rows) -> zero shuffles in QK (was 128
// ds-ops/thread/chunk). float4 staging. 2 barriers/chunk (Ps write/read
// is same-wave: tids rr*4..rr*4+3).
__global__ __launch_bounds__(256) void flash_kernel(const float* __restrict__ qkv,
                                                    unsigned short* __restrict__ o) {
  int qt = blockIdx.x, h = blockIdx.y, b = blockIdx.z;
  int tid = threadIdx.x;
  int rr = tid >> 2, cg = tid & 3;
  __shared__ float Ks[64][68];
  __shared__ float Vs[64][68];
  __shared__ float Ps[64][68];
  const float scale = 0.125f;
  int qrow = qt * 64 + rr;
  bool qvalid = qrow < SS;
  float q[64];
  {
    const float* qp = qkv + (size_t)(b * SS + (qvalid ? qrow : 0)) * 2304 + h * 64;
#pragma unroll
    for (int i = 0; i < 64; i += 4) {
      float4 v = *reinterpret_cast<const float4*>(qp + i);
      q[i + 0] = qvalid ? v.x * scale : 0.f;
      q[i + 1] = qvalid ? v.y * scale : 0.f;
      q[i + 2] = qvalid ? v.z * scale : 0.f;
      q[i + 3] = qvalid ? v.w * scale : 0.f;
    }
  }
  float O[16];
#pragma unroll
  for (int i = 0; i < 16; i++) O[i] = 0.f;
  float mrow = -3e38f, lrow = 0.f;
  for (int kc = 0; kc < 9; kc++) {
    int kbase = kc * 64;
#pragma unroll
    for (int e = tid; e < 1024; e += 256) {
      int krow = e >> 4, d0 = (e & 15) * 4;
      int gk = kbase + krow;
      float4 kv = make_float4(0.f, 0.f, 0.f, 0.f);
      float4 vv = make_float4(0.f, 0.f, 0.f, 0.f);
      if (gk < SS) {
        const float* pk = qkv + (size_t)(b * SS + gk) * 2304 + 768 + h * 64 + d0;
        kv = *reinterpret_cast<const float4*>(pk);
        vv = *reinterpret_cast<const float4*>(pk + 768);
      }
      *reinterpret_cast<float4*>(&Ks[krow][d0]) = kv;
      *reinterpret_cast<float4*>(&Vs[krow][d0]) = vv;
    }
    __syncthreads();
    float svals[16];
    float mc = -3e38f;
#pragma unroll 4
    for (int jj = 0; jj < 16; jj++) {
      int kk = jj * 4 + cg;
      const float* kr = &Ks[kk][0];
      float p0 = 0.f, p1 = 0.f, p2 = 0.f, p3 = 0.f;
#pragma unroll
      for (int i = 0; i < 64; i += 4) {
        float4 kv4 = *reinterpret_cast<const float4*>(kr + i);
        p0 += q[i + 0] * kv4.x; p1 += q[i + 1] * kv4.y;
        p2 += q[i + 2] * kv4.z; p3 += q[i + 3] * kv4.w;
      }
      float p = (p0 + p1) + (p2 + p3);
      float s = (kbase + kk < SS) ? p : -3e38f;
      svals[jj] = s;
      mc = fmaxf(mc, s);
    }
    mc = fmaxf(mc, __shfl_xor(mc, 1));
    mc = fmaxf(mc, __shfl_xor(mc, 2));
    float mnew = fmaxf(mrow, mc);
    float alpha = __expf(mrow - mnew);
    float lsum = 0.f;
#pragma unroll
    for (int jj = 0; jj < 16; jj++) {
      float pexp = __expf(svals[jj] - mnew);
      lsum += pexp;
      Ps[rr][jj * 4 + cg] = pexp;
    }
    lsum += __shfl_xor(lsum, 1);
    lsum += __shfl_xor(lsum, 2);
    lrow = lrow * alpha + lsum;
#pragma unroll
    for (int i = 0; i < 16; i++) O[i] *= alpha;
    mrow = mnew;
#pragma unroll 4
    for (int kk = 0; kk < 64; kk++) {
      float pw = Ps[rr][kk];
      const float* vr = &Vs[kk][cg * 16];
#pragma unroll
      for (int i = 0; i < 16; i++) O[i] += pw * vr[i];
    }
    __syncthreads();
  }
  if (qvalid) {
    float inv = 1.f / lrow;
    unsigned short* op = o + (size_t)(b * SS + qrow) * 768 + h * 64 + cg * 16;
#pragma unroll
    for (int i = 0; i < 16; i++) op[i] = f2b(O[i] * inv);
  }
}

// ---------------------------------------------------------------- launch
extern "C" void kernel_launch(void* const* d_in, const int* in_sizes, int n_in,
                              void* d_out, int out_size, void* d_ws, size_t ws_size,
                              hipStream_t stream) {
  const float* pts    = (const float*)d_in[0];
  const float* colors = (const float*)d_in[1];
  const float* w1a    = (const float*)d_in[2];
  const float* b1a    = (const float*)d_in[3];
  const float* bn1g   = (const float*)d_in[4];
  const float* bn1b   = (const float*)d_in[5];
  const float* bn1m   = (const float*)d_in[6];
  const float* bn1v   = (const float*)d_in[7];
  const float* w1b    = (const float*)d_in[8];
  const float* b1b    = (const float*)d_in[9];
  const float* w2a    = (const float*)d_in[10];
  const float* b2a    = (const float*)d_in[11];
  const float* bn2g   = (const float*)d_in[12];
  const float* bn2b   = (const float*)d_in[13];
  const float* bn2m   = (const float*)d_in[14];
  const float* bn2v   = (const float*)d_in[15];
  const float* w2b    = (const float*)d_in[16];
  const float* b2b    = (const float*)d_in[17];
  const float* e2t_w  = (const float*)d_in[18];
  const float* e2t_b  = (const float*)d_in[19];
  const float* cls_token = (const float*)d_in[20];
  const float* cls_pos   = (const float*)d_in[21];
  const float* pe_w1  = (const float*)d_in[22];
  const float* pe_b1  = (const float*)d_in[23];
  const float* pe_w2  = (const float*)d_in[24];
  const float* pe_b2  = (const float*)d_in[25];
  const float* ln1_g  = (const float*)d_in[26];
  const float* ln1_b  = (const float*)d_in[27];
  const float* qkv_w  = (const float*)d_in[28];
  const float* qkv_b  = (const float*)d_in[29];
  const float* proj_w = (const float*)d_in[30];
  const float* proj_b = (const float*)d_in[31];
  const float* ln2_g  = (const float*)d_in[32];
  const float* ln2_b  = (const float*)d_in[33];
  const float* mlp_w1 = (const float*)d_in[34];
  const float* mlp_b1 = (const float*)d_in[35];
  const float* mlp_w2 = (const float*)d_in[36];
  const float* mlp_b2 = (const float*)d_in[37];
  const float* fcn_g  = (const float*)d_in[38];
  const float* fcn_b  = (const float*)d_in[39];
  const float* t2e_w  = (const float*)d_in[40];
  const float* t2e_b  = (const float*)d_in[41];

  if (ws_size < (size_t)67174400) return;  // insufficient scratch -> fail visibly

  char* ws = (char*)d_ws;
  int*            fidx   = (int*)(ws + 0);
  float*          center = (float*)(ws + 8192);
  int*            knn    = (int*)(ws + 32768);
  unsigned short* tok    = (unsigned short*)(ws + 294912);    // [2048,256] bf16
  float*          xs     = (float*)(ws + 1343488);            // [2052,768] f32
  unsigned short* hbuf   = (unsigned short*)(ws + 7647232);   // [2052,768] bf16
  float*          fbuf   = (float*)(ws + 10799104);           // [2052,768] f32
  char*           WT     = ws + 17102848;                     // weight arena
  unsigned short* qkv_wt = (unsigned short*)(WT + 0);         // [2304,768]
  unsigned short* proj_wt= (unsigned short*)(WT + 3538944);   // [768,768]
  unsigned short* w1t    = (unsigned short*)(WT + 4718592);   // [3072,768]
  unsigned short* w2t    = (unsigned short*)(WT + 9437184);   // [768,3072]
  unsigned short* w1bb   = (unsigned short*)(WT + 14155776);  // [256,128]
  unsigned short* w2ab   = (unsigned short*)(WT + 14221312);  // [512,512]
  unsigned short* w2bb   = (unsigned short*)(WT + 14745600);  // [256,512]
  unsigned short* e2tb   = (unsigned short*)(WT + 15007744);  // [768,256]
  char*           BA     = ws + 32503808;                     // big arena
  unsigned short* f1   = (unsigned short*)(BA + 0);           // [16384,128]
  unsigned short* f2   = (unsigned short*)(BA + 4194304);     // [16384,256]
  unsigned short* fg   = (unsigned short*)(BA + 12582912);    // [512,256]
  unsigned short* f3   = (unsigned short*)(BA + 12845056);    // [16384,512]
  unsigned short* f4   = (unsigned short*)(BA + 0);           // [16384,256]
  float*          tp   = (float*)(BA + 0);                    // [2048,768] f32
  float*          pp   = (float*)(BA + 6291456);              // [2048,768] f32
  float*          hid  = (float*)(BA + 12582912);             // [2048,128] f32
  float*          qkvb = (float*)(BA + 0);                    // [2052,2304] f32
  unsigned short* obuf = (unsigned short*)(BA + 18911232);    // [2052,768] bf16
  unsigned short* mh   = (unsigned short*)(BA + 22063104);    // [2052,3072] bf16

  cvt_kernel<<<32, 256, 0, stream>>>(w1b, w1bb, 32768);
  cvt_kernel<<<256, 256, 0, stream>>>(w2a, w2ab, 262144);
  cvt_kernel<<<128, 256, 0, stream>>>(w2b, w2bb, 131072);
  cvt_kernel<<<192, 256, 0, stream>>>(e2t_w, e2tb, 196608);

  fps_kernel<<<BB, 512, 0, stream>>>(pts, fidx, center);
  knn_kernel<<<BB * GG, 256, 0, stream>>>(pts, center, knn);

  for (int c = 0; c < 4; c++) {
    int gbase = c * 512;
    enc1a_kernel<<<512, 256, 0, stream>>>(pts, colors, knn, center,
        w1a, b1a, bn1g, bn1b, bn1m, bn1v, f1, gbase);
    bgemm<0, 0, 1, 0><<<dim3(2, 128), 256, 0, stream>>>(f1, nullptr, w1bb, b1b,
        nullptr, f2, 16384, 256, 128, nullptr, nullptr, nullptr, nullptr);
    maxpool_kernel<<<512, 256, 0, stream>>>(f2, fg, 512 * 256);
    bgemm<2, 0, 1, 1><<<dim3(4, 128), 256, 0, stream>>>(f2, fg, w2ab, b2a,
        nullptr, f3, 16384, 512, 512, bn2g, bn2b, bn2m, bn2v);
    bgemm<0, 0, 1, 0><<<dim3(2, 128), 256, 0, stream>>>(f3, nullptr, w2bb, b2b,
        nullptr, f4, 16384, 256, 512, nullptr, nullptr, nullptr, nullptr);
    maxpool_kernel<<<512, 256, 0, stream>>>(f4, tok + (size_t)gbase * 256, 512 * 256);
  }

  bgemm<0, 0, 0, 0><<<dim3(6, 16), 256, 0, stream>>>(tok, nullptr, e2tb, e2t_b,
      nullptr, tp, 2048, 768, 256, nullptr, nullptr, nullptr, nullptr);
  pe_hidden_kernel<<<1024, 256, 0, stream>>>(center, pe_w1, pe_b1, hid);
  gemm_kernel<1, 0, 0><<<dim3(12, 32), 256, 0, stream>>>(hid, pe_w2, pe_b2, nullptr, pp, 2048, 768, 128);
  assemble_kernel<<<BB * SS, 256, 0, stream>>>(tp, pp, cls_token, cls_pos, xs);

  for (int i = 0; i < 4; i++) {
    tc_kernel<<<dim3(72, 24), 256, 0, stream>>>(qkv_w + (size_t)i * 768 * 2304, qkv_wt, 768, 2304);
    tc_kernel<<<dim3(24, 24), 256, 0, stream>>>(proj_w + (size_t)i * 768 * 768, proj_wt, 768, 768);
    tc_kernel<<<dim3(96, 24), 256, 0, stream>>>(mlp_w1 + (size_t)i * 768 * 3072, w1t, 768, 3072);
    tc_kernel<<<dim3(24, 96), 256, 0, stream>>>(mlp_w2 + (size_t)i * 3072 * 768, w2t, 3072, 768);

    ln_kernel<1><<<BB * SS, 256, 0, stream>>>(xs, ln1_g + i * 768, ln1_b + i * 768, hbuf);
    bgemm<0, 0, 0, 0><<<dim3(18, 17), 256, 0, stream>>>(hbuf, nullptr, qkv_wt,
        qkv_b + i * 2304, nullptr, qkvb, 2052, 2304, 768, nullptr, nullptr, nullptr, nullptr);
    flash_kernel<<<dim3(9, 12, 4), 256, 0, stream>>>(qkvb, obuf);
    bgemm<0, 1, 0, 0><<<dim3(6, 17), 256, 0, stream>>>(obuf, nullptr, proj_wt,
        proj_b + i * 768, xs, xs, 2052, 768, 768, nullptr, nullptr, nullptr, nullptr);
    ln_kernel<1><<<BB * SS, 256, 0, stream>>>(xs, ln2_g + i * 768, ln2_b + i * 768, hbuf);
    bgemm<1, 0, 1, 0><<<dim3(24, 17), 256, 0, stream>>>(hbuf, nullptr, w1t,
        mlp_b1 + i * 3072, nullptr, mh, 2052, 3072, 768, nullptr, nullptr, nullptr, nullptr);
    bgemm<0, 1, 0, 0><<<dim3(6, 17), 256, 0, stream>>>(mh, nullptr, w2t,
        mlp_b2 + i * 768, xs, xs, 2052, 768, 3072, nullptr, nullptr, nullptr, nullptr);
  }

  ln_kernel<0><<<BB * SS, 256, 0, stream>>>(xs, fcn_g, fcn_b, fbuf);
  gemm_kernel<1, 0, 0><<<dim3(12, 33), 256, 0, stream>>>(fbuf, t2e_w, t2e_b, nullptr,
      (float*)d_out, 2052, 768, 768);
}

// Round 9
// 2689.127 us; speedup vs baseline: 2.9165x; 1.0174x over previous
//
#include <hip/hip_runtime.h>
#include <math.h>

#define BB 4
#define NN 8192
#define GG 512
#define KK 32
#define DD 768
#define SS 513
#define HH 12

typedef __attribute__((ext_vector_type(8))) short bf16x8;
typedef __attribute__((ext_vector_type(4))) float f32x4;
typedef __attribute__((ext_vector_type(2))) float f32x2;

__device__ __forceinline__ float gelu_f(float x) {
  return 0.5f * x * (1.f + erff(x * 0.70710678118654752f));
}
__device__ __forceinline__ unsigned short f2b(float f) {
  unsigned u = __float_as_uint(f);
  u = (u + 0x7FFFu + ((u >> 16) & 1u)) >> 16;
  return (unsigned short)u;
}
__device__ __forceinline__ float b2f(unsigned short h) {
  return __uint_as_float(((unsigned)h) << 16);
}

// Packed fp32 (2 lanes-worth per instruction). Exact: v_pk_mul/add_f32 are two
// independent IEEE RTE f32 ops — identical rounding to scalar v_mul/v_add.
__device__ __forceinline__ f32x2 pk_add(f32x2 a, f32x2 b) {
  f32x2 r;
  asm("v_pk_add_f32 %0, %1, %2" : "=v"(r) : "v"(a), "v"(b));
  return r;
}
__device__ __forceinline__ f32x2 pk_mul(f32x2 a, f32x2 b) {
  f32x2 r;
  asm("v_pk_mul_f32 %0, %1, %2" : "=v"(r) : "v"(a), "v"(b));
  return r;
}

// 64-lane reductions via DPP (VALU-only).
__device__ __forceinline__ unsigned wave_max_u32(unsigned v) {
  unsigned t;
  t = (unsigned)__builtin_amdgcn_update_dpp(0, (int)v, 0x111, 0xf, 0xf, false); v = t > v ? t : v;
  t = (unsigned)__builtin_amdgcn_update_dpp(0, (int)v, 0x112, 0xf, 0xf, false); v = t > v ? t : v;
  t = (unsigned)__builtin_amdgcn_update_dpp(0, (int)v, 0x114, 0xf, 0xf, false); v = t > v ? t : v;
  t = (unsigned)__builtin_amdgcn_update_dpp(0, (int)v, 0x118, 0xf, 0xf, false); v = t > v ? t : v;
  t = (unsigned)__builtin_amdgcn_update_dpp(0, (int)v, 0x142, 0xf, 0xf, false); v = t > v ? t : v;
  t = (unsigned)__builtin_amdgcn_update_dpp(0, (int)v, 0x143, 0xf, 0xf, false); v = t > v ? t : v;
  return (unsigned)__builtin_amdgcn_readlane((int)v, 63);
}
__device__ __forceinline__ unsigned wave_min_u32(unsigned v) {
  unsigned t;
  t = (unsigned)__builtin_amdgcn_update_dpp(0x7FFFFFFF, (int)v, 0x111, 0xf, 0xf, false); v = t < v ? t : v;
  t = (unsigned)__builtin_amdgcn_update_dpp(0x7FFFFFFF, (int)v, 0x112, 0xf, 0xf, false); v = t < v ? t : v;
  t = (unsigned)__builtin_amdgcn_update_dpp(0x7FFFFFFF, (int)v, 0x114, 0xf, 0xf, false); v = t < v ? t : v;
  t = (unsigned)__builtin_amdgcn_update_dpp(0x7FFFFFFF, (int)v, 0x118, 0xf, 0xf, false); v = t < v ? t : v;
  t = (unsigned)__builtin_amdgcn_update_dpp(0x7FFFFFFF, (int)v, 0x142, 0xf, 0xf, false); v = t < v ? t : v;
  t = (unsigned)__builtin_amdgcn_update_dpp(0x7FFFFFFF, (int)v, 0x143, 0xf, 0xf, false); v = t < v ? t : v;
  return (unsigned)__builtin_amdgcn_readlane((int)v, 63);
}

// ---------------------------------------------------------------- FPS
// One block per batch, 512 threads x 16 BLOCKED points (pair-packed for pk ops).
// ONE barrier per iteration: DPP wave reduce -> lane0 writes double-buffered
// wave key -> barrier -> all threads scan 8 keys -> winner coords read straight
// from the LDS point table (no atomic, no 2nd barrier, no scx chain).
// Exactness vs numpy: sub = add(-c) (bit-exact), separate muls, (xx+yy)+zz
// order, no FMA; lowest-index tiebreak in-thread (reverse scan), via ~idx in
// key cross-thread.
__global__ __launch_bounds__(512) void fps_kernel(const float* __restrict__ pts,
                                                  int* __restrict__ fidx,
                                                  float* __restrict__ center) {
  int b = blockIdx.x, tid = threadIdx.x;
  const float* P = pts + (size_t)b * NN * 3;
  __shared__ float pl[NN * 3];                 // 96 KB point table
  __shared__ unsigned long long skey[2][8];    // double-buffered wave keys
  f32x2 x2[8], y2[8], z2[8], dmin2[8];
  int base = tid * 16;
#pragma unroll
  for (int m = 0; m < 8; m++) {
    const float* p0 = P + (size_t)(base + 2 * m) * 3;
    float a0 = p0[0], a1 = p0[1], a2 = p0[2], a3 = p0[3], a4 = p0[4], a5 = p0[5];
    x2[m].x = a0; x2[m].y = a3;
    y2[m].x = a1; y2[m].y = a4;
    z2[m].x = a2; z2[m].y = a5;
    dmin2[m].x = 1e10f; dmin2[m].y = 1e10f;
    float* q = &pl[(base + 2 * m) * 3];
    q[0] = a0; q[1] = a1; q[2] = a2; q[3] = a3; q[4] = a4; q[5] = a5;
  }
  __syncthreads();
  if (tid == 0) {
    fidx[b * GG] = 0;
    center[(size_t)(b * GG) * 3 + 0] = pl[0];
    center[(size_t)(b * GG) * 3 + 1] = pl[1];
    center[(size_t)(b * GG) * 3 + 2] = pl[2];
  }
  unsigned widx = 0;
  for (int it = 0; it < GG - 1; it++) {
    float cx = pl[widx * 3 + 0], cy = pl[widx * 3 + 1], cz = pl[widx * 3 + 2];
    f32x2 ncx, ncy, ncz;
    ncx.x = -cx; ncx.y = -cx;
    ncy.x = -cy; ncy.y = -cy;
    ncz.x = -cz; ncz.y = -cz;
    float bv = -1.f;
#pragma unroll
    for (int m = 0; m < 8; m++) {
      f32x2 dx = pk_add(x2[m], ncx);
      f32x2 dy = pk_add(y2[m], ncy);
      f32x2 dz = pk_add(z2[m], ncz);
      f32x2 xx = pk_mul(dx, dx);
      f32x2 yy = pk_mul(dy, dy);
      f32x2 zz = pk_mul(dz, dz);
      f32x2 d  = pk_add(pk_add(xx, yy), zz);
      f32x2 dm;
      dm.x = fminf(dmin2[m].x, d.x);
      dm.y = fminf(dmin2[m].y, d.y);
      dmin2[m] = dm;
      bv = fmaxf(bv, fmaxf(dm.x, dm.y));
    }
    unsigned bi = 0xFFFFFFFFu;
#pragma unroll
    for (int m = 7; m >= 0; m--) {    // reverse: final assignment = lowest idx
      if (dmin2[m].y == bv) bi = (unsigned)(base + 2 * m + 1);
      if (dmin2[m].x == bv) bi = (unsigned)(base + 2 * m);
    }
    unsigned bvb = __float_as_uint(bv);             // nonneg: bit order == float order
    unsigned wmax = wave_max_u32(bvb);
    unsigned cand = (bvb == wmax) ? bi : 0xFFFFFFFFu;
    unsigned wi = wave_min_u32(cand);
    if ((tid & 63) == 0)
      skey[it & 1][tid >> 6] =
          ((unsigned long long)wmax << 32) | (unsigned long long)(0xFFFFFFFFu - wi);
    __syncthreads();
    unsigned long long bk = skey[it & 1][0];
#pragma unroll
    for (int ww = 1; ww < 8; ww++) {
      unsigned long long k = skey[it & 1][ww];
      bk = (k > bk) ? k : bk;
    }
    widx = 0xFFFFFFFFu - (unsigned)(bk & 0xFFFFFFFFu);
    if (tid == 0) {
      fidx[b * GG + it + 1] = (int)widx;
      center[(size_t)(b * GG + it + 1) * 3 + 0] = pl[widx * 3 + 0];
      center[(size_t)(b * GG + it + 1) * 3 + 1] = pl[widx * 3 + 1];
      center[(size_t)(b * GG + it + 1) * 3 + 2] = pl[widx * 3 + 2];
    }
  }
}

// ---------------------------------------------------------------- KNN (unchanged)
__global__ __launch_bounds__(256) void knn_kernel(const float* __restrict__ pts,
                                                  const float* __restrict__ center,
                                                  int* __restrict__ knn_idx) {
  int bg = blockIdx.x;
  int b = bg >> 9;
  int tid = threadIdx.x;
  __shared__ float dist[NN];
  __shared__ unsigned long long sred[4];
  const float* P = pts + (size_t)b * NN * 3;
  float cx = center[bg * 3 + 0], cy = center[bg * 3 + 1], cz = center[bg * 3 + 2];
  for (int j = 0; j < 32; j++) {
    int p = tid + 256 * j;
    float dx = P[p * 3 + 0] - cx, dy = P[p * 3 + 1] - cy, dz = P[p * 3 + 2] - cz;
    dist[p] = dx * dx + dy * dy + dz * dz;
  }
  __syncthreads();
  for (int r = 0; r < KK; r++) {
    unsigned long long best = 0xFFFFFFFFFFFFFFFFull;
#pragma unroll 8
    for (int j = 0; j < 32; j++) {
      int p = tid + 256 * j;
      unsigned long long key = ((unsigned long long)__float_as_uint(dist[p]) << 32) | (unsigned)p;
      best = (key < best) ? key : best;
    }
#pragma unroll
    for (int off = 32; off > 0; off >>= 1) {
      unsigned long long o = __shfl_xor(best, off);
      best = (o < best) ? o : best;
    }
    int lane = tid & 63, wid = tid >> 6;
    if (lane == 0) sred[wid] = best;
    __syncthreads();
    if (tid < 4) {
      unsigned long long v = sred[tid];
      unsigned long long o = __shfl_xor(v, 1); v = (o < v) ? o : v;
      o = __shfl_xor(v, 2); v = (o < v) ? o : v;
      if (tid == 0) {
        int p = (int)(v & 0xFFFFFFFFu);
        knn_idx[bg * KK + r] = p;
        dist[p] = 3.0e38f;
      }
    }
    __syncthreads();
  }
}

// ---------------------------------------------------------------- convert fp32 -> bf16
__global__ __launch_bounds__(256) void cvt_kernel(const float* __restrict__ s,
                                                  unsigned short* __restrict__ d, int n) {
  int i = (blockIdx.x * 256 + threadIdx.x) * 4;
  if (i + 3 < n) {
    float4 v = *reinterpret_cast<const float4*>(&s[i]);
    d[i + 0] = f2b(v.x); d[i + 1] = f2b(v.y); d[i + 2] = f2b(v.z); d[i + 3] = f2b(v.w);
  }
}

// ---------------------------------------------------------------- transpose-convert: src[K,N] f32 -> dst[N,K] bf16
__global__ __launch_bounds__(256) void tc_kernel(const float* __restrict__ src,
                                                 unsigned short* __restrict__ dst,
                                                 int K, int N) {
  __shared__ float t[32][33];
  int n0 = blockIdx.x * 32, k0 = blockIdx.y * 32;
  int tx = threadIdx.x & 31, ty = threadIdx.x >> 5;  // 32 x 8
#pragma unroll
  for (int i = 0; i < 32; i += 8)
    t[ty + i][tx] = src[(size_t)(k0 + ty + i) * N + n0 + tx];
  __syncthreads();
#pragma unroll
  for (int i = 0; i < 32; i += 8)
    dst[(size_t)(n0 + ty + i) * K + k0 + tx] = f2b(t[tx][ty + i]);
}

// ---------------------------------------------------------------- encoder stage 1a
__global__ __launch_bounds__(256) void enc1a_kernel(
    const float* __restrict__ pts, const float* __restrict__ colors,
    const int* __restrict__ knn_idx, const float* __restrict__ center,
    const float* __restrict__ w1a, const float* __restrict__ b1a,
    const float* __restrict__ bn1g, const float* __restrict__ bn1b,
    const float* __restrict__ bn1m, const float* __restrict__ bn1v,
    unsigned short* __restrict__ f1, int gbase)
{
  int g = gbase + blockIdx.x;
  int b = g >> 9;
  int tid = threadIdx.x;
  __shared__ float feat[KK][8];
  if (tid < 192) {
    int k = tid / 6, c = tid % 6;
    int p = knn_idx[g * KK + k];
    float v;
    if (c < 3) v = pts[(size_t)(b * NN + p) * 3 + c] - center[g * 3 + c];
    else       v = colors[(size_t)(b * NN + p) * 3 + (c - 3)];
    feat[k][c] = v;
  }
  __syncthreads();
  for (int e = tid; e < KK * 128; e += 256) {
    int k = e >> 7, j = e & 127;
    float s = b1a[j];
#pragma unroll
    for (int c = 0; c < 6; c++) s += feat[k][c] * w1a[j * 6 + c];
    s = (s - bn1m[j]) * rsqrtf(bn1v[j] + 1e-5f) * bn1g[j] + bn1b[j];
    f1[((size_t)blockIdx.x * KK + k) * 128 + j] = f2b(fmaxf(s, 0.f));
  }
}

// ---------------------------------------------------------------- maxpool over 32 points (bf16), C=256
__global__ __launch_bounds__(256) void maxpool_kernel(const unsigned short* __restrict__ in,
                                                      unsigned short* __restrict__ out, int total) {
  int e = blockIdx.x * 256 + threadIdx.x;
  if (e >= total) return;
  int g = e >> 8, c = e & 255;
  const unsigned short* p = in + ((size_t)g * 32) * 256 + c;
  float m = -3e38f;
#pragma unroll 8
  for (int k = 0; k < 32; k++) m = fmaxf(m, b2f(p[k * 256]));
  out[e] = f2b(m);
}

// ---------------------------------------------------------------- bf16 MFMA GEMM
template <int ACT, int RESID, int OUTBF, int CONCAT>
__global__ __launch_bounds__(256) void bgemm(
    const unsigned short* __restrict__ A, const unsigned short* __restrict__ fg,
    const unsigned short* __restrict__ W, const float* __restrict__ bias,
    const float* __restrict__ resid, void* __restrict__ outp,
    int M, int N, int K,
    const float* __restrict__ bng, const float* __restrict__ bnb,
    const float* __restrict__ bnm, const float* __restrict__ bnv)
{
  __shared__ unsigned short As[128][40];
  __shared__ unsigned short Bs[128][40];
  const int tid = threadIdx.x;
  const int tm0 = blockIdx.y * 128, tn0 = blockIdx.x * 128;
  const int w = tid >> 6, l = tid & 63;
  const int wr = (w >> 1) * 64, wc = (w & 1) * 64;
  const int lr = l & 15, lk = l >> 4;

  f32x4 zero4 = {0.f, 0.f, 0.f, 0.f};
  f32x4 acc[4][4];
#pragma unroll
  for (int m = 0; m < 4; m++)
#pragma unroll
    for (int n = 0; n < 4; n++) acc[m][n] = zero4;

  for (int k0 = 0; k0 < K; k0 += 32) {
#pragma unroll
    for (int c = 0; c < 2; c++) {
      int s = tid + c * 256;
      int row = s >> 2, kp = s & 3;
      uint4 va = make_uint4(0u, 0u, 0u, 0u);
      int grow = tm0 + row;
      if (grow < M) {
        if (CONCAT) {
          int kk = k0 + kp * 8;
          const unsigned short* src = (kk < 256)
              ? &fg[((size_t)(grow >> 5)) * 256 + kk]
              : &A[(size_t)grow * 256 + (kk - 256)];
          va = *reinterpret_cast<const uint4*>(src);
        } else {
          va = *reinterpret_cast<const uint4*>(&A[(size_t)grow * K + k0 + kp * 8]);
        }
      }
      *reinterpret_cast<uint4*>(&As[row][kp * 8]) = va;
      uint4 vb = *reinterpret_cast<const uint4*>(&W[(size_t)(tn0 + row) * K + k0 + kp * 8]);
      *reinterpret_cast<uint4*>(&Bs[row][kp * 8]) = vb;
    }
    __syncthreads();
    bf16x8 af[4], bfr[4];
#pragma unroll
    for (int m = 0; m < 4; m++)
      af[m] = *reinterpret_cast<const bf16x8*>(&As[wr + m * 16 + lr][lk * 8]);
#pragma unroll
    for (int n = 0; n < 4; n++)
      bfr[n] = *reinterpret_cast<const bf16x8*>(&Bs[wc + n * 16 + lr][lk * 8]);
#pragma unroll
    for (int m = 0; m < 4; m++)
#pragma unroll
      for (int n = 0; n < 4; n++)
        acc[m][n] = __builtin_amdgcn_mfma_f32_16x16x32_bf16(af[m], bfr[n], acc[m][n], 0, 0, 0);
    __syncthreads();
  }
#pragma unroll
  for (int m = 0; m < 4; m++) {
#pragma unroll
    for (int r = 0; r < 4; r++) {
      int row = tm0 + wr + m * 16 + lk * 4 + r;
      if (row >= M) continue;
#pragma unroll
      for (int n = 0; n < 4; n++) {
        int col = tn0 + wc + n * 16 + lr;
        float v = acc[m][n][r] + bias[col];
        if (ACT == 1) v = gelu_f(v);
        if (ACT == 2) {
          v = (v - bnm[col]) * rsqrtf(bnv[col] + 1e-5f) * bng[col] + bnb[col];
          v = fmaxf(v, 0.f);
        }
        if (RESID) v += resid[(size_t)row * N + col];
        if (OUTBF) ((unsigned short*)outp)[(size_t)row * N + col] = f2b(v);
        else       ((float*)outp)[(size_t)row * N + col] = v;
      }
    }
  }
}

// ---------------------------------------------------------------- fp32 GEMM (pe + final t2e)
template <int TRANSB, int ACT, int RESID>
__global__ __launch_bounds__(256) void gemm_kernel(
    const float* __restrict__ A, const float* __restrict__ W,
    const float* __restrict__ bias, const float* __restrict__ resid,
    float* __restrict__ out, int M, int N, int K)
{
  __shared__ float Asm[16][64];
  __shared__ float Bsm[16][64];
  int tile_n = blockIdx.x * 64, tile_m = blockIdx.y * 64;
  int tid = threadIdx.x;
  int tm = tid >> 4, tn = tid & 15;
  float acc[4][4] = {};
  for (int k0 = 0; k0 < K; k0 += 16) {
    {
      int e = tid * 4;
      int m = e >> 4, k = e & 15;
      int row = tile_m + m;
      float4 v = make_float4(0.f, 0.f, 0.f, 0.f);
      if (row < M) v = *reinterpret_cast<const float4*>(&A[(size_t)row * K + k0 + k]);
      Asm[k + 0][m] = v.x; Asm[k + 1][m] = v.y; Asm[k + 2][m] = v.z; Asm[k + 3][m] = v.w;
    }
    if (TRANSB == 0) {
      int e = tid * 4;
      int n = e & 63, k = e >> 6;
      float4 v = *reinterpret_cast<const float4*>(&W[(size_t)(k0 + k) * N + tile_n + n]);
      *reinterpret_cast<float4*>(&Bsm[k][n]) = v;
    } else {
      int e = tid * 4;
      int k = e & 15, n = e >> 4;
      float4 v = *reinterpret_cast<const float4*>(&W[(size_t)(tile_n + n) * K + k0 + k]);
      Bsm[k + 0][n] = v.x; Bsm[k + 1][n] = v.y; Bsm[k + 2][n] = v.z; Bsm[k + 3][n] = v.w;
    }
    __syncthreads();
#pragma unroll
    for (int kk = 0; kk < 16; kk++) {
      float4 a = *reinterpret_cast<const float4*>(&Asm[kk][tm * 4]);
      float4 wv = *reinterpret_cast<const float4*>(&Bsm[kk][tn * 4]);
      acc[0][0] += a.x * wv.x; acc[0][1] += a.x * wv.y; acc[0][2] += a.x * wv.z; acc[0][3] += a.x * wv.w;
      acc[1][0] += a.y * wv.x; acc[1][1] += a.y * wv.y; acc[1][2] += a.y * wv.z; acc[1][3] += a.y * wv.w;
      acc[2][0] += a.z * wv.x; acc[2][1] += a.z * wv.y; acc[2][2] += a.z * wv.z; acc[2][3] += a.z * wv.w;
      acc[3][0] += a.w * wv.x; acc[3][1] += a.w * wv.y; acc[3][2] += a.w * wv.z; acc[3][3] += a.w * wv.w;
    }
    __syncthreads();
  }
#pragma unroll
  for (int i = 0; i < 4; i++) {
    int row = tile_m + tm * 4 + i;
    if (row >= M) continue;
    int col = tile_n + tn * 4;
    float4 r;
    r.x = acc[i][0] + bias[col + 0];
    r.y = acc[i][1] + bias[col + 1];
    r.z = acc[i][2] + bias[col + 2];
    r.w = acc[i][3] + bias[col + 3];
    if (ACT == 1) { r.x = gelu_f(r.x); r.y = gelu_f(r.y); r.z = gelu_f(r.z); r.w = gelu_f(r.w); }
    if (RESID) {
      float4 rr = *reinterpret_cast<const float4*>(&resid[(size_t)row * N + col]);
      r.x += rr.x; r.y += rr.y; r.z += rr.z; r.w += rr.w;
    }
    *reinterpret_cast<float4*>(&out[(size_t)row * N + col]) = r;
  }
}

// ---------------------------------------------------------------- LayerNorm
template <int OUTBF>
__global__ __launch_bounds__(256) void ln_kernel(const float* __restrict__ x,
                                                 const float* __restrict__ g,
                                                 const float* __restrict__ bta,
                                                 void* __restrict__ yv) {
  int r = blockIdx.x;
  int tid = threadIdx.x;
  __shared__ float sred[4];
  __shared__ float smu, srs;
  const float* xr = x + (size_t)r * 768;
  float v0 = xr[tid], v1 = xr[tid + 256], v2 = xr[tid + 512];
  float s = v0 + v1 + v2;
#pragma unroll
  for (int off = 32; off > 0; off >>= 1) s += __shfl_xor(s, off);
  if ((tid & 63) == 0) sred[tid >> 6] = s;
  __syncthreads();
  if (tid < 4) {
    float t = sred[tid];
    t += __shfl_xor(t, 1); t += __shfl_xor(t, 2);
    if (tid == 0) smu = t * (1.f / 768.f);
  }
  __syncthreads();
  float mu = smu;
  float d0 = v0 - mu, d1 = v1 - mu, d2 = v2 - mu;
  float ss = d0 * d0 + d1 * d1 + d2 * d2;
#pragma unroll
  for (int off = 32; off > 0; off >>= 1) ss += __shfl_xor(ss, off);
  if ((tid & 63) == 0) sred[tid >> 6] = ss;
  __syncthreads();
  if (tid < 4) {
    float t = sred[tid];
    t += __shfl_xor(t, 1); t += __shfl_xor(t, 2);
    if (tid == 0) srs = rsqrtf(t * (1.f / 768.f) + 1e-5f);
  }
  __syncthreads();
  float rs = srs;
  float o0 = d0 * rs * g[tid]       + bta[tid];
  float o1 = d1 * rs * g[tid + 256] + bta[tid + 256];
  float o2 = d2 * rs * g[tid + 512] + bta[tid + 512];
  if (OUTBF) {
    unsigned short* yr = (unsigned short*)yv + (size_t)r * 768;
    yr[tid] = f2b(o0); yr[tid + 256] = f2b(o1); yr[tid + 512] = f2b(o2);
  } else {
    float* yr = (float*)yv + (size_t)r * 768;
    yr[tid] = o0; yr[tid + 256] = o1; yr[tid + 512] = o2;
  }
}

// ---------------------------------------------------------------- pos-embed hidden
__global__ __launch_bounds__(256) void pe_hidden_kernel(const float* __restrict__ center,
                                                        const float* __restrict__ w1,
                                                        const float* __restrict__ b1,
                                                        float* __restrict__ hid) {
  int e = blockIdx.x * 256 + threadIdx.x;
  int r = e >> 7, j = e & 127;
  float cx = center[r * 3 + 0], cy = center[r * 3 + 1], cz = center[r * 3 + 2];
  float s = b1[j] + cx * w1[j * 3 + 0] + cy * w1[j * 3 + 1] + cz * w1[j * 3 + 2];
  hid[e] = gelu_f(s);
}

// ---------------------------------------------------------------- assemble xs
__global__ __launch_bounds__(256) void assemble_kernel(const float* __restrict__ tp,
                                                       const float* __restrict__ pp,
                                                       const float* __restrict__ cls_tok,
                                                       const float* __restrict__ cls_pos,
                                                       float* __restrict__ xs) {
  int r = blockIdx.x;
  int b = r / SS, t = r % SS;
  int tid = threadIdx.x;
  float* xr = xs + (size_t)r * 768;
  if (t == 0) {
    for (int d = tid; d < 768; d += 256) xr[d] = cls_tok[d] + cls_pos[d];
  } else {
    int g = b * GG + (t - 1);
    for (int d = tid; d < 768; d += 256) xr[d] = tp[(size_t)g * 768 + d] + pp[(size_t)g * 768 + d];
  }
}

// ---------------------------------------------------------------- flash attention (fp32 in, bf16 out)
__global__ __launch_bounds__(256) void flash_kernel(const float* __restrict__ qkv,
                                                    unsigned short* __restrict__ o) {
  int qt = blockIdx.x, h = blockIdx.y, b = blockIdx.z;
  int tid = threadIdx.x;
  int rr = tid >> 2, cg = tid & 3;
  __shared__ float Ks[64][68];
  __shared__ float Vs[64][68];
  __shared__ float Ps[64][68];
  const float scale = 0.125f;
  int qrow = qt * 64 + rr;
  bool qvalid = qrow < SS;
  float q[64];
  {
    const float* qp = qkv + (size_t)(b * SS + (qvalid ? qrow : 0)) * 2304 + h * 64;
#pragma unroll
    for (int i = 0; i < 64; i += 4) {
      float4 v = *reinterpret_cast<const float4*>(qp + i);
      q[i + 0] = qvalid ? v.x * scale : 0.f;
      q[i + 1] = qvalid ? v.y * scale : 0.f;
      q[i + 2] = qvalid ? v.z * scale : 0.f;
      q[i + 3] = qvalid ? v.w * scale : 0.f;
    }
  }
  float O[16];
#pragma unroll
  for (int i = 0; i < 16; i++) O[i] = 0.f;
  float mrow = -3e38f, lrow = 0.f;
  for (int kc = 0; kc < 9; kc++) {
    int kbase = kc * 64;
#pragma unroll
    for (int e = tid; e < 1024; e += 256) {
      int krow = e >> 4, d0 = (e & 15) * 4;
      int gk = kbase + krow;
      float4 kv = make_float4(0.f, 0.f, 0.f, 0.f);
      float4 vv = make_float4(0.f, 0.f, 0.f, 0.f);
      if (gk < SS) {
        const float* pk = qkv + (size_t)(b * SS + gk) * 2304 + 768 + h * 64 + d0;
        kv = *reinterpret_cast<const float4*>(pk);
        vv = *reinterpret_cast<const float4*>(pk + 768);
      }
      *reinterpret_cast<float4*>(&Ks[krow][d0]) = kv;
      *reinterpret_cast<float4*>(&Vs[krow][d0]) = vv;
    }
    __syncthreads();
    float svals[16];
    float mc = -3e38f;
#pragma unroll 4
    for (int jj = 0; jj < 16; jj++) {
      int kk = jj * 4 + cg;
      const float* kr = &Ks[kk][0];
      float p0 = 0.f, p1 = 0.f, p2 = 0.f, p3 = 0.f;
#pragma unroll
      for (int i = 0; i < 64; i += 4) {
        float4 kv4 = *reinterpret_cast<const float4*>(kr + i);
        p0 += q[i + 0] * kv4.x; p1 += q[i + 1] * kv4.y;
        p2 += q[i + 2] * kv4.z; p3 += q[i + 3] * kv4.w;
      }
      float p = (p0 + p1) + (p2 + p3);
      float s = (kbase + kk < SS) ? p : -3e38f;
      svals[jj] = s;
      mc = fmaxf(mc, s);
    }
    mc = fmaxf(mc, __shfl_xor(mc, 1));
    mc = fmaxf(mc, __shfl_xor(mc, 2));
    float mnew = fmaxf(mrow, mc);
    float alpha = __expf(mrow - mnew);
    float lsum = 0.f;
#pragma unroll
    for (int jj = 0; jj < 16; jj++) {
      float pexp = __expf(svals[jj] - mnew);
      lsum += pexp;
      Ps[rr][jj * 4 + cg] = pexp;
    }
    lsum += __shfl_xor(lsum, 1);
    lsum += __shfl_xor(lsum, 2);
    lrow = lrow * alpha + lsum;
#pragma unroll
    for (int i = 0; i < 16; i++) O[i] *= alpha;
    mrow = mnew;
#pragma unroll 4
    for (int kk = 0; kk < 64; kk++) {
      float pw = Ps[rr][kk];
      const float* vr = &Vs[kk][cg * 16];
#pragma unroll
      for (int i = 0; i < 16; i++) O[i] += pw * vr[i];
    }
    __syncthreads();
  }
  if (qvalid) {
    float inv = 1.f / lrow;
    unsigned short* op = o + (size_t)(b * SS + qrow) * 768 + h * 64 + cg * 16;
#pragma unroll
    for (int i = 0; i < 16; i++) op[i] = f2b(O[i] * inv);
  }
}

// ---------------------------------------------------------------- launch
extern "C" void kernel_launch(void* const* d_in, const int* in_sizes, int n_in,
                              void* d_out, int out_size, void* d_ws, size_t ws_size,
                              hipStream_t stream) {
  const float* pts    = (const float*)d_in[0];
  const float* colors = (const float*)d_in[1];
  const float* w1a    = (const float*)d_in[2];
  const float* b1a    = (const float*)d_in[3];
  const float* bn1g   = (const float*)d_in[4];
  const float* bn1b   = (const float*)d_in[5];
  const float* bn1m   = (const float*)d_in[6];
  const float* bn1v   = (const float*)d_in[7];
  const float* w1b    = (const float*)d_in[8];
  const float* b1b    = (const float*)d_in[9];
  const float* w2a    = (const float*)d_in[10];
  const float* b2a    = (const float*)d_in[11];
  const float* bn2g   = (const float*)d_in[12];
  const float* bn2b   = (const float*)d_in[13];
  const float* bn2m   = (const float*)d_in[14];
  const float* bn2v   = (const float*)d_in[15];
  const float* w2b    = (const float*)d_in[16];
  const float* b2b    = (const float*)d_in[17];
  const float* e2t_w  = (const float*)d_in[18];
  const float* e2t_b  = (const float*)d_in[19];
  const float* cls_token = (const float*)d_in[20];
  const float* cls_pos   = (const float*)d_in[21];
  const float* pe_w1  = (const float*)d_in[22];
  const float* pe_b1  = (const float*)d_in[23];
  const float* pe_w2  = (const float*)d_in[24];
  const float* pe_b2  = (const float*)d_in[25];
  const float* ln1_g  = (const float*)d_in[26];
  const float* ln1_b  = (const float*)d_in[27];
  const float* qkv_w  = (const float*)d_in[28];
  const float* qkv_b  = (const float*)d_in[29];
  const float* proj_w = (const float*)d_in[30];
  const float* proj_b = (const float*)d_in[31];
  const float* ln2_g  = (const float*)d_in[32];
  const float* ln2_b  = (const float*)d_in[33];
  const float* mlp_w1 = (const float*)d_in[34];
  const float* mlp_b1 = (const float*)d_in[35];
  const float* mlp_w2 = (const float*)d_in[36];
  const float* mlp_b2 = (const float*)d_in[37];
  const float* fcn_g  = (const float*)d_in[38];
  const float* fcn_b  = (const float*)d_in[39];
  const float* t2e_w  = (const float*)d_in[40];
  const float* t2e_b  = (const float*)d_in[41];

  if (ws_size < (size_t)67174400) return;  // insufficient scratch -> fail visibly

  char* ws = (char*)d_ws;
  int*            fidx   = (int*)(ws + 0);
  float*          center = (float*)(ws + 8192);
  int*            knn    = (int*)(ws + 32768);
  unsigned short* tok    = (unsigned short*)(ws + 294912);    // [2048,256] bf16
  float*          xs     = (float*)(ws + 1343488);            // [2052,768] f32
  unsigned short* hbuf   = (unsigned short*)(ws + 7647232);   // [2052,768] bf16
  float*          fbuf   = (float*)(ws + 10799104);           // [2052,768] f32
  char*           WT     = ws + 17102848;                     // weight arena
  unsigned short* qkv_wt = (unsigned short*)(WT + 0);         // [2304,768]
  unsigned short* proj_wt= (unsigned short*)(WT + 3538944);   // [768,768]
  unsigned short* w1t    = (unsigned short*)(WT + 4718592);   // [3072,768]
  unsigned short* w2t    = (unsigned short*)(WT + 9437184);   // [768,3072]
  unsigned short* w1bb   = (unsigned short*)(WT + 14155776);  // [256,128]
  unsigned short* w2ab   = (unsigned short*)(WT + 14221312);  // [512,512]
  unsigned short* w2bb   = (unsigned short*)(WT + 14745600);  // [256,512]
  unsigned short* e2tb   = (unsigned short*)(WT + 15007744);  // [768,256]
  char*           BA     = ws + 32503808;                     // big arena
  unsigned short* f1   = (unsigned short*)(BA + 0);           // [16384,128]
  unsigned short* f2   = (unsigned short*)(BA + 4194304);     // [16384,256]
  unsigned short* fg   = (unsigned short*)(BA + 12582912);    // [512,256]
  unsigned short* f3   = (unsigned short*)(BA + 12845056);    // [16384,512]
  unsigned short* f4   = (unsigned short*)(BA + 0);           // [16384,256]
  float*          tp   = (float*)(BA + 0);                    // [2048,768] f32
  float*          pp   = (float*)(BA + 6291456);              // [2048,768] f32
  float*          hid  = (float*)(BA + 12582912);             // [2048,128] f32
  float*          qkvb = (float*)(BA + 0);                    // [2052,2304] f32
  unsigned short* obuf = (unsigned short*)(BA + 18911232);    // [2052,768] bf16
  unsigned short* mh   = (unsigned short*)(BA + 22063104);    // [2052,3072] bf16

  cvt_kernel<<<32, 256, 0, stream>>>(w1b, w1bb, 32768);
  cvt_kernel<<<256, 256, 0, stream>>>(w2a, w2ab, 262144);
  cvt_kernel<<<128, 256, 0, stream>>>(w2b, w2bb, 131072);
  cvt_kernel<<<192, 256, 0, stream>>>(e2t_w, e2tb, 196608);

  fps_kernel<<<BB, 512, 0, stream>>>(pts, fidx, center);
  knn_kernel<<<BB * GG, 256, 0, stream>>>(pts, center, knn);

  for (int c = 0; c < 4; c++) {
    int gbase = c * 512;
    enc1a_kernel<<<512, 256, 0, stream>>>(pts, colors, knn, center,
        w1a, b1a, bn1g, bn1b, bn1m, bn1v, f1, gbase);
    bgemm<0, 0, 1, 0><<<dim3(2, 128), 256, 0, stream>>>(f1, nullptr, w1bb, b1b,
        nullptr, f2, 16384, 256, 128, nullptr, nullptr, nullptr, nullptr);
    maxpool_kernel<<<512, 256, 0, stream>>>(f2, fg, 512 * 256);
    bgemm<2, 0, 1, 1><<<dim3(4, 128), 256, 0, stream>>>(f2, fg, w2ab, b2a,
        nullptr, f3, 16384, 512, 512, bn2g, bn2b, bn2m, bn2v);
    bgemm<0, 0, 1, 0><<<dim3(2, 128), 256, 0, stream>>>(f3, nullptr, w2bb, b2b,
        nullptr, f4, 16384, 256, 512, nullptr, nullptr, nullptr, nullptr);
    maxpool_kernel<<<512, 256, 0, stream>>>(f4, tok + (size_t)gbase * 256, 512 * 256);
  }

  bgemm<0, 0, 0, 0><<<dim3(6, 16), 256, 0, stream>>>(tok, nullptr, e2tb, e2t_b,
      nullptr, tp, 2048, 768, 256, nullptr, nullptr, nullptr, nullptr);
  pe_hidden_kernel<<<1024, 256, 0, stream>>>(center, pe_w1, pe_b1, hid);
  gemm_kernel<1, 0, 0><<<dim3(12, 32), 256, 0, stream>>>(hid, pe_w2, pe_b2, nullptr, pp, 2048, 768, 128);
  assemble_kernel<<<BB * SS, 256, 0, stream>>>(tp, pp, cls_token, cls_pos, xs);

  for (int i = 0; i < 4; i++) {
    tc_kernel<<<dim3(72, 24), 256, 0, stream>>>(qkv_w + (size_t)i * 768 * 2304, qkv_wt, 768, 2304);
    tc_kernel<<<dim3(24, 24), 256, 0, stream>>>(proj_w + (size_t)i * 768 * 768, proj_wt, 768, 768);
    tc_kernel<<<dim3(96, 24), 256, 0, stream>>>(mlp_w1 + (size_t)i * 768 * 3072, w1t, 768, 3072);
    tc_kernel<<<dim3(24, 96), 256, 0, stream>>>(mlp_w2 + (size_t)i * 3072 * 768, w2t, 3072, 768);

    ln_kernel<1><<<BB * SS, 256, 0, stream>>>(xs, ln1_g + i * 768, ln1_b + i * 768, hbuf);
    bgemm<0, 0, 0, 0><<<dim3(18, 17), 256, 0, stream>>>(hbuf, nullptr, qkv_wt,
        qkv_b + i * 2304, nullptr, qkvb, 2052, 2304, 768, nullptr, nullptr, nullptr, nullptr);
    flash_kernel<<<dim3(9, 12, 4), 256, 0, stream>>>(qkvb, obuf);
    bgemm<0, 1, 0, 0><<<dim3(6, 17), 256, 0, stream>>>(obuf, nullptr, proj_wt,
        proj_b + i * 768, xs, xs, 2052, 768, 768, nullptr, nullptr, nullptr, nullptr);
    ln_kernel<1><<<BB * SS, 256, 0, stream>>>(xs, ln2_g + i * 768, ln2_b + i * 768, hbuf);
    bgemm<1, 0, 1, 0><<<dim3(24, 17), 256, 0, stream>>>(hbuf, nullptr, w1t,
        mlp_b1 + i * 3072, nullptr, mh, 2052, 3072, 768, nullptr, nullptr, nullptr, nullptr);
    bgemm<0, 1, 0, 0><<<dim3(6, 17), 256, 0, stream>>>(mh, nullptr, w2t,
        mlp_b2 + i * 768, xs, xs, 2052, 768, 3072, nullptr, nullptr, nullptr, nullptr);
  }

  ln_kernel<0><<<BB * SS, 256, 0, stream>>>(xs, fcn_g, fcn_b, fbuf);
  gemm_kernel<1, 0, 0><<<dim3(12, 33), 256, 0, stream>>>(fbuf, t2e_w, t2e_b, nullptr,
      (float*)d_out, 2052, 768, 768);
}

// Round 10
// 2599.860 us; speedup vs baseline: 3.0167x; 1.0343x over previous
//
#include <hip/hip_runtime.h>
#include <math.h>

#define BB 4
#define NN 8192
#define GG 512
#define KK 32
#define DD 768
#define SS 513
#define HH 12

typedef __attribute__((ext_vector_type(8))) short bf16x8;
typedef __attribute__((ext_vector_type(4))) float f32x4;
typedef __attribute__((ext_vector_type(2))) float f32x2;

__device__ __forceinline__ float gelu_f(float x) {
  return 0.5f * x * (1.f + erff(x * 0.70710678118654752f));
}
__device__ __forceinline__ unsigned short f2b(float f) {
  unsigned u = __float_as_uint(f);
  u = (u + 0x7FFFu + ((u >> 16) & 1u)) >> 16;
  return (unsigned short)u;
}
__device__ __forceinline__ float b2f(unsigned short h) {
  return __uint_as_float(((unsigned)h) << 16);
}

// Async global->LDS 16B (direct, no VGPR roundtrip). LDS dest is
// wave-uniform base + lane*16; global src is per-lane.
__device__ __forceinline__ void gld16(void* lds, const void* g) {
  __builtin_amdgcn_global_load_lds(
      (const __attribute__((address_space(1))) unsigned int*)g,
      (__attribute__((address_space(3))) unsigned int*)lds, 16, 0, 0);
}

// Packed fp32 (2 lanes-worth per instruction). Exact: v_pk_mul/add_f32 are two
// independent IEEE RTE f32 ops — identical rounding to scalar v_mul/v_add.
__device__ __forceinline__ f32x2 pk_add(f32x2 a, f32x2 b) {
  f32x2 r;
  asm("v_pk_add_f32 %0, %1, %2" : "=v"(r) : "v"(a), "v"(b));
  return r;
}
__device__ __forceinline__ f32x2 pk_mul(f32x2 a, f32x2 b) {
  f32x2 r;
  asm("v_pk_mul_f32 %0, %1, %2" : "=v"(r) : "v"(a), "v"(b));
  return r;
}

// 64-lane reductions via DPP (VALU-only).
__device__ __forceinline__ unsigned wave_max_u32(unsigned v) {
  unsigned t;
  t = (unsigned)__builtin_amdgcn_update_dpp(0, (int)v, 0x111, 0xf, 0xf, false); v = t > v ? t : v;
  t = (unsigned)__builtin_amdgcn_update_dpp(0, (int)v, 0x112, 0xf, 0xf, false); v = t > v ? t : v;
  t = (unsigned)__builtin_amdgcn_update_dpp(0, (int)v, 0x114, 0xf, 0xf, false); v = t > v ? t : v;
  t = (unsigned)__builtin_amdgcn_update_dpp(0, (int)v, 0x118, 0xf, 0xf, false); v = t > v ? t : v;
  t = (unsigned)__builtin_amdgcn_update_dpp(0, (int)v, 0x142, 0xf, 0xf, false); v = t > v ? t : v;
  t = (unsigned)__builtin_amdgcn_update_dpp(0, (int)v, 0x143, 0xf, 0xf, false); v = t > v ? t : v;
  return (unsigned)__builtin_amdgcn_readlane((int)v, 63);
}
__device__ __forceinline__ unsigned wave_min_u32(unsigned v) {
  unsigned t;
  t = (unsigned)__builtin_amdgcn_update_dpp(0x7FFFFFFF, (int)v, 0x111, 0xf, 0xf, false); v = t < v ? t : v;
  t = (unsigned)__builtin_amdgcn_update_dpp(0x7FFFFFFF, (int)v, 0x112, 0xf, 0xf, false); v = t < v ? t : v;
  t = (unsigned)__builtin_amdgcn_update_dpp(0x7FFFFFFF, (int)v, 0x114, 0xf, 0xf, false); v = t < v ? t : v;
  t = (unsigned)__builtin_amdgcn_update_dpp(0x7FFFFFFF, (int)v, 0x118, 0xf, 0xf, false); v = t < v ? t : v;
  t = (unsigned)__builtin_amdgcn_update_dpp(0x7FFFFFFF, (int)v, 0x142, 0xf, 0xf, false); v = t < v ? t : v;
  t = (unsigned)__builtin_amdgcn_update_dpp(0x7FFFFFFF, (int)v, 0x143, 0xf, 0xf, false); v = t < v ? t : v;
  return (unsigned)__builtin_amdgcn_readlane((int)v, 63);
}

// ---------------------------------------------------------------- FPS (unchanged from r9; VALU floor reached)
__global__ __launch_bounds__(512) void fps_kernel(const float* __restrict__ pts,
                                                  int* __restrict__ fidx,
                                                  float* __restrict__ center) {
  int b = blockIdx.x, tid = threadIdx.x;
  const float* P = pts + (size_t)b * NN * 3;
  __shared__ float pl[NN * 3];                 // 96 KB point table
  __shared__ unsigned long long skey[2][8];    // double-buffered wave keys
  f32x2 x2[8], y2[8], z2[8], dmin2[8];
  int base = tid * 16;
#pragma unroll
  for (int m = 0; m < 8; m++) {
    const float* p0 = P + (size_t)(base + 2 * m) * 3;
    float a0 = p0[0], a1 = p0[1], a2 = p0[2], a3 = p0[3], a4 = p0[4], a5 = p0[5];
    x2[m].x = a0; x2[m].y = a3;
    y2[m].x = a1; y2[m].y = a4;
    z2[m].x = a2; z2[m].y = a5;
    dmin2[m].x = 1e10f; dmin2[m].y = 1e10f;
    float* q = &pl[(base + 2 * m) * 3];
    q[0] = a0; q[1] = a1; q[2] = a2; q[3] = a3; q[4] = a4; q[5] = a5;
  }
  __syncthreads();
  if (tid == 0) {
    fidx[b * GG] = 0;
    center[(size_t)(b * GG) * 3 + 0] = pl[0];
    center[(size_t)(b * GG) * 3 + 1] = pl[1];
    center[(size_t)(b * GG) * 3 + 2] = pl[2];
  }
  unsigned widx = 0;
  for (int it = 0; it < GG - 1; it++) {
    float cx = pl[widx * 3 + 0], cy = pl[widx * 3 + 1], cz = pl[widx * 3 + 2];
    f32x2 ncx, ncy, ncz;
    ncx.x = -cx; ncx.y = -cx;
    ncy.x = -cy; ncy.y = -cy;
    ncz.x = -cz; ncz.y = -cz;
    float bv = -1.f;
#pragma unroll
    for (int m = 0; m < 8; m++) {
      f32x2 dx = pk_add(x2[m], ncx);
      f32x2 dy = pk_add(y2[m], ncy);
      f32x2 dz = pk_add(z2[m], ncz);
      f32x2 xx = pk_mul(dx, dx);
      f32x2 yy = pk_mul(dy, dy);
      f32x2 zz = pk_mul(dz, dz);
      f32x2 d  = pk_add(pk_add(xx, yy), zz);
      f32x2 dm;
      dm.x = fminf(dmin2[m].x, d.x);
      dm.y = fminf(dmin2[m].y, d.y);
      dmin2[m] = dm;
      bv = fmaxf(bv, fmaxf(dm.x, dm.y));
    }
    unsigned bi = 0xFFFFFFFFu;
#pragma unroll
    for (int m = 7; m >= 0; m--) {    // reverse: final assignment = lowest idx
      if (dmin2[m].y == bv) bi = (unsigned)(base + 2 * m + 1);
      if (dmin2[m].x == bv) bi = (unsigned)(base + 2 * m);
    }
    unsigned bvb = __float_as_uint(bv);
    unsigned wmax = wave_max_u32(bvb);
    unsigned cand = (bvb == wmax) ? bi : 0xFFFFFFFFu;
    unsigned wi = wave_min_u32(cand);
    if ((tid & 63) == 0)
      skey[it & 1][tid >> 6] =
          ((unsigned long long)wmax << 32) | (unsigned long long)(0xFFFFFFFFu - wi);
    __syncthreads();
    unsigned long long bk = skey[it & 1][0];
#pragma unroll
    for (int ww = 1; ww < 8; ww++) {
      unsigned long long k = skey[it & 1][ww];
      bk = (k > bk) ? k : bk;
    }
    widx = 0xFFFFFFFFu - (unsigned)(bk & 0xFFFFFFFFu);
    if (tid == 0) {
      fidx[b * GG + it + 1] = (int)widx;
      center[(size_t)(b * GG + it + 1) * 3 + 0] = pl[widx * 3 + 0];
      center[(size_t)(b * GG + it + 1) * 3 + 1] = pl[widx * 3 + 1];
      center[(size_t)(b * GG + it + 1) * 3 + 2] = pl[widx * 3 + 2];
    }
  }
}

// ---------------------------------------------------------------- KNN (unchanged)
__global__ __launch_bounds__(256) void knn_kernel(const float* __restrict__ pts,
                                                  const float* __restrict__ center,
                                                  int* __restrict__ knn_idx) {
  int bg = blockIdx.x;
  int b = bg >> 9;
  int tid = threadIdx.x;
  __shared__ float dist[NN];
  __shared__ unsigned long long sred[4];
  const float* P = pts + (size_t)b * NN * 3;
  float cx = center[bg * 3 + 0], cy = center[bg * 3 + 1], cz = center[bg * 3 + 2];
  for (int j = 0; j < 32; j++) {
    int p = tid + 256 * j;
    float dx = P[p * 3 + 0] - cx, dy = P[p * 3 + 1] - cy, dz = P[p * 3 + 2] - cz;
    dist[p] = dx * dx + dy * dy + dz * dz;
  }
  __syncthreads();
  for (int r = 0; r < KK; r++) {
    unsigned long long best = 0xFFFFFFFFFFFFFFFFull;
#pragma unroll 8
    for (int j = 0; j < 32; j++) {
      int p = tid + 256 * j;
      unsigned long long key = ((unsigned long long)__float_as_uint(dist[p]) << 32) | (unsigned)p;
      best = (key < best) ? key : best;
    }
#pragma unroll
    for (int off = 32; off > 0; off >>= 1) {
      unsigned long long o = __shfl_xor(best, off);
      best = (o < best) ? o : best;
    }
    int lane = tid & 63, wid = tid >> 6;
    if (lane == 0) sred[wid] = best;
    __syncthreads();
    if (tid < 4) {
      unsigned long long v = sred[tid];
      unsigned long long o = __shfl_xor(v, 1); v = (o < v) ? o : v;
      o = __shfl_xor(v, 2); v = (o < v) ? o : v;
      if (tid == 0) {
        int p = (int)(v & 0xFFFFFFFFu);
        knn_idx[bg * KK + r] = p;
        dist[p] = 3.0e38f;
      }
    }
    __syncthreads();
  }
}

// ---------------------------------------------------------------- convert fp32 -> bf16
__global__ __launch_bounds__(256) void cvt_kernel(const float* __restrict__ s,
                                                  unsigned short* __restrict__ d, int n) {
  int i = (blockIdx.x * 256 + threadIdx.x) * 4;
  if (i + 3 < n) {
    float4 v = *reinterpret_cast<const float4*>(&s[i]);
    d[i + 0] = f2b(v.x); d[i + 1] = f2b(v.y); d[i + 2] = f2b(v.z); d[i + 3] = f2b(v.w);
  }
}

// ---------------------------------------------------------------- transpose-convert: src[K,N] f32 -> dst[N,K] bf16
__global__ __launch_bounds__(256) void tc_kernel(const float* __restrict__ src,
                                                 unsigned short* __restrict__ dst,
                                                 int K, int N) {
  __shared__ float t[32][33];
  int n0 = blockIdx.x * 32, k0 = blockIdx.y * 32;
  int tx = threadIdx.x & 31, ty = threadIdx.x >> 5;  // 32 x 8
#pragma unroll
  for (int i = 0; i < 32; i += 8)
    t[ty + i][tx] = src[(size_t)(k0 + ty + i) * N + n0 + tx];
  __syncthreads();
#pragma unroll
  for (int i = 0; i < 32; i += 8)
    dst[(size_t)(n0 + ty + i) * K + k0 + tx] = f2b(t[tx][ty + i]);
}

// ---------------------------------------------------------------- encoder stage 1a
__global__ __launch_bounds__(256) void enc1a_kernel(
    const float* __restrict__ pts, const float* __restrict__ colors,
    const int* __restrict__ knn_idx, const float* __restrict__ center,
    const float* __restrict__ w1a, const float* __restrict__ b1a,
    const float* __restrict__ bn1g, const float* __restrict__ bn1b,
    const float* __restrict__ bn1m, const float* __restrict__ bn1v,
    unsigned short* __restrict__ f1, int gbase)
{
  int g = gbase + blockIdx.x;
  int b = g >> 9;
  int tid = threadIdx.x;
  __shared__ float feat[KK][8];
  if (tid < 192) {
    int k = tid / 6, c = tid % 6;
    int p = knn_idx[g * KK + k];
    float v;
    if (c < 3) v = pts[(size_t)(b * NN + p) * 3 + c] - center[g * 3 + c];
    else       v = colors[(size_t)(b * NN + p) * 3 + (c - 3)];
    feat[k][c] = v;
  }
  __syncthreads();
  for (int e = tid; e < KK * 128; e += 256) {
    int k = e >> 7, j = e & 127;
    float s = b1a[j];
#pragma unroll
    for (int c = 0; c < 6; c++) s += feat[k][c] * w1a[j * 6 + c];
    s = (s - bn1m[j]) * rsqrtf(bn1v[j] + 1e-5f) * bn1g[j] + bn1b[j];
    f1[((size_t)blockIdx.x * KK + k) * 128 + j] = f2b(fmaxf(s, 0.f));
  }
}

// ---------------------------------------------------------------- maxpool over 32 points (bf16), C=256
__global__ __launch_bounds__(256) void maxpool_kernel(const unsigned short* __restrict__ in,
                                                      unsigned short* __restrict__ out, int total) {
  int e = blockIdx.x * 256 + threadIdx.x;
  if (e >= total) return;
  int g = e >> 8, c = e & 255;
  const unsigned short* p = in + ((size_t)g * 32) * 256 + c;
  float m = -3e38f;
#pragma unroll 8
  for (int k = 0; k < 32; k++) m = fmaxf(m, b2f(p[k * 256]));
  out[e] = f2b(m);
}

// ---------------------------------------------------------------- bf16 MFMA GEMM (m97-style: linear LDS + global_load_lds w16)
template <int ACT, int RESID, int OUTBF, int CONCAT>
__global__ __launch_bounds__(256) void bgemm(
    const unsigned short* __restrict__ A, const unsigned short* __restrict__ fg,
    const unsigned short* __restrict__ W, const float* __restrict__ bias,
    const float* __restrict__ resid, void* __restrict__ outp,
    int M, int N, int K,
    const float* __restrict__ bng, const float* __restrict__ bnb,
    const float* __restrict__ bnm, const float* __restrict__ bnv)
{
  __shared__ unsigned short As[128][32];   // linear: required by global_load_lds
  __shared__ unsigned short Bs[128][32];
  const int tid = threadIdx.x;
  const int tm0 = blockIdx.y * 128, tn0 = blockIdx.x * 128;
  const int w = tid >> 6, l = tid & 63;
  const int wr = (w >> 1) * 64, wc = (w & 1) * 64;
  const int lr = l & 15, lk = l >> 4;

  f32x4 zero4 = {0.f, 0.f, 0.f, 0.f};
  f32x4 acc[4][4];
#pragma unroll
  for (int m = 0; m < 4; m++)
#pragma unroll
    for (int n = 0; n < 4; n++) acc[m][n] = zero4;

  for (int k0 = 0; k0 < K; k0 += 32) {
#pragma unroll
    for (int c = 0; c < 2; c++) {
      int chunk = c * 256 + tid;        // 0..511 : (row = chunk>>2, 16B piece = chunk&3)
      int row = chunk >> 2, kp = chunk & 3;
      int grow = tm0 + row;
      int r2 = (grow < M) ? grow : 0;   // OOB rows: load row 0 (garbage, never written)
      const unsigned short* ga;
      if (CONCAT) {
        int kk = k0 + kp * 8;
        ga = (kk < 256) ? &fg[((size_t)(r2 >> 5)) * 256 + kk]
                        : &A[(size_t)r2 * 256 + (kk - 256)];
      } else {
        ga = &A[(size_t)r2 * K + k0 + kp * 8];
      }
      gld16(&As[0][0] + (size_t)chunk * 8, ga);
      gld16(&Bs[0][0] + (size_t)chunk * 8, &W[(size_t)(tn0 + row) * K + k0 + kp * 8]);
    }
    __syncthreads();
    bf16x8 af[4], bfr[4];
#pragma unroll
    for (int m = 0; m < 4; m++)
      af[m] = *reinterpret_cast<const bf16x8*>(&As[wr + m * 16 + lr][lk * 8]);
#pragma unroll
    for (int n = 0; n < 4; n++)
      bfr[n] = *reinterpret_cast<const bf16x8*>(&Bs[wc + n * 16 + lr][lk * 8]);
#pragma unroll
    for (int m = 0; m < 4; m++)
#pragma unroll
      for (int n = 0; n < 4; n++)
        acc[m][n] = __builtin_amdgcn_mfma_f32_16x16x32_bf16(af[m], bfr[n], acc[m][n], 0, 0, 0);
    __syncthreads();
  }
#pragma unroll
  for (int m = 0; m < 4; m++) {
#pragma unroll
    for (int r = 0; r < 4; r++) {
      int row = tm0 + wr + m * 16 + lk * 4 + r;
      if (row >= M) continue;
#pragma unroll
      for (int n = 0; n < 4; n++) {
        int col = tn0 + wc + n * 16 + lr;
        float v = acc[m][n][r] + bias[col];
        if (ACT == 1) v = gelu_f(v);
        if (ACT == 2) {
          v = (v - bnm[col]) * rsqrtf(bnv[col] + 1e-5f) * bng[col] + bnb[col];
          v = fmaxf(v, 0.f);
        }
        if (RESID) v += resid[(size_t)row * N + col];
        if (OUTBF) ((unsigned short*)outp)[(size_t)row * N + col] = f2b(v);
        else       ((float*)outp)[(size_t)row * N + col] = v;
      }
    }
  }
}

// ---------------------------------------------------------------- fp32 GEMM (pe + final t2e)
template <int TRANSB, int ACT, int RESID>
__global__ __launch_bounds__(256) void gemm_kernel(
    const float* __restrict__ A, const float* __restrict__ W,
    const float* __restrict__ bias, const float* __restrict__ resid,
    float* __restrict__ out, int M, int N, int K)
{
  __shared__ float Asm[16][64];
  __shared__ float Bsm[16][64];
  int tile_n = blockIdx.x * 64, tile_m = blockIdx.y * 64;
  int tid = threadIdx.x;
  int tm = tid >> 4, tn = tid & 15;
  float acc[4][4] = {};
  for (int k0 = 0; k0 < K; k0 += 16) {
    {
      int e = tid * 4;
      int m = e >> 4, k = e & 15;
      int row = tile_m + m;
      float4 v = make_float4(0.f, 0.f, 0.f, 0.f);
      if (row < M) v = *reinterpret_cast<const float4*>(&A[(size_t)row * K + k0 + k]);
      Asm[k + 0][m] = v.x; Asm[k + 1][m] = v.y; Asm[k + 2][m] = v.z; Asm[k + 3][m] = v.w;
    }
    if (TRANSB == 0) {
      int e = tid * 4;
      int n = e & 63, k = e >> 6;
      float4 v = *reinterpret_cast<const float4*>(&W[(size_t)(k0 + k) * N + tile_n + n]);
      *reinterpret_cast<float4*>(&Bsm[k][n]) = v;
    } else {
      int e = tid * 4;
      int k = e & 15, n = e >> 4;
      float4 v = *reinterpret_cast<const float4*>(&W[(size_t)(tile_n + n) * K + k0 + k]);
      Bsm[k + 0][n] = v.x; Bsm[k + 1][n] = v.y; Bsm[k + 2][n] = v.z; Bsm[k + 3][n] = v.w;
    }
    __syncthreads();
#pragma unroll
    for (int kk = 0; kk < 16; kk++) {
      float4 a = *reinterpret_cast<const float4*>(&Asm[kk][tm * 4]);
      float4 wv = *reinterpret_cast<const float4*>(&Bsm[kk][tn * 4]);
      acc[0][0] += a.x * wv.x; acc[0][1] += a.x * wv.y; acc[0][2] += a.x * wv.z; acc[0][3] += a.x * wv.w;
      acc[1][0] += a.y * wv.x; acc[1][1] += a.y * wv.y; acc[1][2] += a.y * wv.z; acc[1][3] += a.y * wv.w;
      acc[2][0] += a.z * wv.x; acc[2][1] += a.z * wv.y; acc[2][2] += a.z * wv.z; acc[2][3] += a.z * wv.w;
      acc[3][0] += a.w * wv.x; acc[3][1] += a.w * wv.y; acc[3][2] += a.w * wv.z; acc[3][3] += a.w * wv.w;
    }
    __syncthreads();
  }
#pragma unroll
  for (int i = 0; i < 4; i++) {
    int row = tile_m + tm * 4 + i;
    if (row >= M) continue;
    int col = tile_n + tn * 4;
    float4 r;
    r.x = acc[i][0] + bias[col + 0];
    r.y = acc[i][1] + bias[col + 1];
    r.z = acc[i][2] + bias[col + 2];
    r.w = acc[i][3] + bias[col + 3];
    if (ACT == 1) { r.x = gelu_f(r.x); r.y = gelu_f(r.y); r.z = gelu_f(r.z); r.w = gelu_f(r.w); }
    if (RESID) {
      float4 rr = *reinterpret_cast<const float4*>(&resid[(size_t)row * N + col]);
      r.x += rr.x; r.y += rr.y; r.z += rr.z; r.w += rr.w;
    }
    *reinterpret_cast<float4*>(&out[(size_t)row * N + col]) = r;
  }
}

// ---------------------------------------------------------------- LayerNorm
template <int OUTBF>
__global__ __launch_bounds__(256) void ln_kernel(const float* __restrict__ x,
                                                 const float* __restrict__ g,
                                                 const float* __restrict__ bta,
                                                 void* __restrict__ yv) {
  int r = blockIdx.x;
  int tid = threadIdx.x;
  __shared__ float sred[4];
  __shared__ float smu, srs;
  const float* xr = x + (size_t)r * 768;
  float v0 = xr[tid], v1 = xr[tid + 256], v2 = xr[tid + 512];
  float s = v0 + v1 + v2;
#pragma unroll
  for (int off = 32; off > 0; off >>= 1) s += __shfl_xor(s, off);
  if ((tid & 63) == 0) sred[tid >> 6] = s;
  __syncthreads();
  if (tid < 4) {
    float t = sred[tid];
    t += __shfl_xor(t, 1); t += __shfl_xor(t, 2);
    if (tid == 0) smu = t * (1.f / 768.f);
  }
  __syncthreads();
  float mu = smu;
  float d0 = v0 - mu, d1 = v1 - mu, d2 = v2 - mu;
  float ss = d0 * d0 + d1 * d1 + d2 * d2;
#pragma unroll
  for (int off = 32; off > 0; off >>= 1) ss += __shfl_xor(ss, off);
  if ((tid & 63) == 0) sred[tid >> 6] = ss;
  __syncthreads();
  if (tid < 4) {
    float t = sred[tid];
    t += __shfl_xor(t, 1); t += __shfl_xor(t, 2);
    if (tid == 0) srs = rsqrtf(t * (1.f / 768.f) + 1e-5f);
  }
  __syncthreads();
  float rs = srs;
  float o0 = d0 * rs * g[tid]       + bta[tid];
  float o1 = d1 * rs * g[tid + 256] + bta[tid + 256];
  float o2 = d2 * rs * g[tid + 512] + bta[tid + 512];
  if (OUTBF) {
    unsigned short* yr = (unsigned short*)yv + (size_t)r * 768;
    yr[tid] = f2b(o0); yr[tid + 256] = f2b(o1); yr[tid + 512] = f2b(o2);
  } else {
    float* yr = (float*)yv + (size_t)r * 768;
    yr[tid] = o0; yr[tid + 256] = o1; yr[tid + 512] = o2;
  }
}

// ---------------------------------------------------------------- pos-embed hidden
__global__ __launch_bounds__(256) void pe_hidden_kernel(const float* __restrict__ center,
                                                        const float* __restrict__ w1,
                                                        const float* __restrict__ b1,
                                                        float* __restrict__ hid) {
  int e = blockIdx.x * 256 + threadIdx.x;
  int r = e >> 7, j = e & 127;
  float cx = center[r * 3 + 0], cy = center[r * 3 + 1], cz = center[r * 3 + 2];
  float s = b1[j] + cx * w1[j * 3 + 0] + cy * w1[j * 3 + 1] + cz * w1[j * 3 + 2];
  hid[e] = gelu_f(s);
}

// ---------------------------------------------------------------- assemble xs
__global__ __launch_bounds__(256) void assemble_kernel(const float* __restrict__ tp,
                                                       const float* __restrict__ pp,
                                                       const float* __restrict__ cls_tok,
                                                       const float* __restrict__ cls_pos,
                                                       float* __restrict__ xs) {
  int r = blockIdx.x;
  int b = r / SS, t = r % SS;
  int tid = threadIdx.x;
  float* xr = xs + (size_t)r * 768;
  if (t == 0) {
    for (int d = tid; d < 768; d += 256) xr[d] = cls_tok[d] + cls_pos[d];
  } else {
    int g = b * GG + (t - 1);
    for (int d = tid; d < 768; d += 256) xr[d] = tp[(size_t)g * 768 + d] + pp[(size_t)g * 768 + d];
  }
}

// ---------------------------------------------------------------- flash attention (fp32 in, bf16 out)
__global__ __launch_bounds__(256) void flash_kernel(const float* __restrict__ qkv,
                                                    unsigned short* __restrict__ o) {
  int qt = blockIdx.x, h = blockIdx.y, b = blockIdx.z;
  int tid = threadIdx.x;
  int rr = tid >> 2, cg = tid & 3;
  __shared__ float Ks[64][68];
  __shared__ float Vs[64][68];
  __shared__ float Ps[64][68];
  const float scale = 0.125f;
  int qrow = qt * 64 + rr;
  bool qvalid = qrow < SS;
  float q[64];
  {
    const float* qp = qkv + (size_t)(b * SS + (qvalid ? qrow : 0)) * 2304 + h * 64;
#pragma unroll
    for (int i = 0; i < 64; i += 4) {
      float4 v = *reinterpret_cast<const float4*>(qp + i);
      q[i + 0] = qvalid ? v.x * scale : 0.f;
      q[i + 1] = qvalid ? v.y * scale : 0.f;
      q[i + 2] = qvalid ? v.z * scale : 0.f;
      q[i + 3] = qvalid ? v.w * scale : 0.f;
    }
  }
  float O[16];
#pragma unroll
  for (int i = 0; i < 16; i++) O[i] = 0.f;
  float mrow = -3e38f, lrow = 0.f;
  for (int kc = 0; kc < 9; kc++) {
    int kbase = kc * 64;
#pragma unroll
    for (int e = tid; e < 1024; e += 256) {
      int krow = e >> 4, d0 = (e & 15) * 4;
      int gk = kbase + krow;
      float4 kv = make_float4(0.f, 0.f, 0.f, 0.f);
      float4 vv = make_float4(0.f, 0.f, 0.f, 0.f);
      if (gk < SS) {
        const float* pk = qkv + (size_t)(b * SS + gk) * 2304 + 768 + h * 64 + d0;
        kv = *reinterpret_cast<const float4*>(pk);
        vv = *reinterpret_cast<const float4*>(pk + 768);
      }
      *reinterpret_cast<float4*>(&Ks[krow][d0]) = kv;
      *reinterpret_cast<float4*>(&Vs[krow][d0]) = vv;
    }
    __syncthreads();
    float svals[16];
    float mc = -3e38f;
#pragma unroll 4
    for (int jj = 0; jj < 16; jj++) {
      int kk = jj * 4 + cg;
      const float* kr = &Ks[kk][0];
      float p0 = 0.f, p1 = 0.f, p2 = 0.f, p3 = 0.f;
#pragma unroll
      for (int i = 0; i < 64; i += 4) {
        float4 kv4 = *reinterpret_cast<const float4*>(kr + i);
        p0 += q[i + 0] * kv4.x; p1 += q[i + 1] * kv4.y;
        p2 += q[i + 2] * kv4.z; p3 += q[i + 3] * kv4.w;
      }
      float p = (p0 + p1) + (p2 + p3);
      float s = (kbase + kk < SS) ? p : -3e38f;
      svals[jj] = s;
      mc = fmaxf(mc, s);
    }
    mc = fmaxf(mc, __shfl_xor(mc, 1));
    mc = fmaxf(mc, __shfl_xor(mc, 2));
    float mnew = fmaxf(mrow, mc);
    float alpha = __expf(mrow - mnew);
    float lsum = 0.f;
#pragma unroll
    for (int jj = 0; jj < 16; jj++) {
      float pexp = __expf(svals[jj] - mnew);
      lsum += pexp;
      Ps[rr][jj * 4 + cg] = pexp;
    }
    lsum += __shfl_xor(lsum, 1);
    lsum += __shfl_xor(lsum, 2);
    lrow = lrow * alpha + lsum;
#pragma unroll
    for (int i = 0; i < 16; i++) O[i] *= alpha;
    mrow = mnew;
#pragma unroll 4
    for (int kk = 0; kk < 64; kk++) {
      float pw = Ps[rr][kk];
      const float* vr = &Vs[kk][cg * 16];
#pragma unroll
      for (int i = 0; i < 16; i++) O[i] += pw * vr[i];
    }
    __syncthreads();
  }
  if (qvalid) {
    float inv = 1.f / lrow;
    unsigned short* op = o + (size_t)(b * SS + qrow) * 768 + h * 64 + cg * 16;
#pragma unroll
    for (int i = 0; i < 16; i++) op[i] = f2b(O[i] * inv);
  }
}

// ---------------------------------------------------------------- launch
extern "C" void kernel_launch(void* const* d_in, const int* in_sizes, int n_in,
                              void* d_out, int out_size, void* d_ws, size_t ws_size,
                              hipStream_t stream) {
  const float* pts    = (const float*)d_in[0];
  const float* colors = (const float*)d_in[1];
  const float* w1a    = (const float*)d_in[2];
  const float* b1a    = (const float*)d_in[3];
  const float* bn1g   = (const float*)d_in[4];
  const float* bn1b   = (const float*)d_in[5];
  const float* bn1m   = (const float*)d_in[6];
  const float* bn1v   = (const float*)d_in[7];
  const float* w1b    = (const float*)d_in[8];
  const float* b1b    = (const float*)d_in[9];
  const float* w2a    = (const float*)d_in[10];
  const float* b2a    = (const float*)d_in[11];
  const float* bn2g   = (const float*)d_in[12];
  const float* bn2b   = (const float*)d_in[13];
  const float* bn2m   = (const float*)d_in[14];
  const float* bn2v   = (const float*)d_in[15];
  const float* w2b    = (const float*)d_in[16];
  const float* b2b    = (const float*)d_in[17];
  const float* e2t_w  = (const float*)d_in[18];
  const float* e2t_b  = (const float*)d_in[19];
  const float* cls_token = (const float*)d_in[20];
  const float* cls_pos   = (const float*)d_in[21];
  const float* pe_w1  = (const float*)d_in[22];
  const float* pe_b1  = (const float*)d_in[23];
  const float* pe_w2  = (const float*)d_in[24];
  const float* pe_b2  = (const float*)d_in[25];
  const float* ln1_g  = (const float*)d_in[26];
  const float* ln1_b  = (const float*)d_in[27];
  const float* qkv_w  = (const float*)d_in[28];
  const float* qkv_b  = (const float*)d_in[29];
  const float* proj_w = (const float*)d_in[30];
  const float* proj_b = (const float*)d_in[31];
  const float* ln2_g  = (const float*)d_in[32];
  const float* ln2_b  = (const float*)d_in[33];
  const float* mlp_w1 = (const float*)d_in[34];
  const float* mlp_b1 = (const float*)d_in[35];
  const float* mlp_w2 = (const float*)d_in[36];
  const float* mlp_b2 = (const float*)d_in[37];
  const float* fcn_g  = (const float*)d_in[38];
  const float* fcn_b  = (const float*)d_in[39];
  const float* t2e_w  = (const float*)d_in[40];
  const float* t2e_b  = (const float*)d_in[41];

  if (ws_size < (size_t)67174400) return;  // insufficient scratch -> fail visibly

  char* ws = (char*)d_ws;
  int*            fidx   = (int*)(ws + 0);
  float*          center = (float*)(ws + 8192);
  int*            knn    = (int*)(ws + 32768);
  unsigned short* tok    = (unsigned short*)(ws + 294912);    // [2048,256] bf16
  float*          xs     = (float*)(ws + 1343488);            // [2052,768] f32
  unsigned short* hbuf   = (unsigned short*)(ws + 7647232);   // [2052,768] bf16
  float*          fbuf   = (float*)(ws + 10799104);           // [2052,768] f32
  char*           WT     = ws + 17102848;                     // weight arena
  unsigned short* qkv_wt = (unsigned short*)(WT + 0);         // [2304,768]
  unsigned short* proj_wt= (unsigned short*)(WT + 3538944);   // [768,768]
  unsigned short* w1t    = (unsigned short*)(WT + 4718592);   // [3072,768]
  unsigned short* w2t    = (unsigned short*)(WT + 9437184);   // [768,3072]
  unsigned short* w1bb   = (unsigned short*)(WT + 14155776);  // [256,128]
  unsigned short* w2ab   = (unsigned short*)(WT + 14221312);  // [512,512]
  unsigned short* w2bb   = (unsigned short*)(WT + 14745600);  // [256,512]
  unsigned short* e2tb   = (unsigned short*)(WT + 15007744);  // [768,256]
  char*           BA     = ws + 32503808;                     // big arena
  unsigned short* f1   = (unsigned short*)(BA + 0);           // [16384,128]
  unsigned short* f2   = (unsigned short*)(BA + 4194304);     // [16384,256]
  unsigned short* fg   = (unsigned short*)(BA + 12582912);    // [512,256]
  unsigned short* f3   = (unsigned short*)(BA + 12845056);    // [16384,512]
  unsigned short* f4   = (unsigned short*)(BA + 0);           // [16384,256]
  float*          tp   = (float*)(BA + 0);                    // [2048,768] f32
  float*          pp   = (float*)(BA + 6291456);              // [2048,768] f32
  float*          hid  = (float*)(BA + 12582912);             // [2048,128] f32
  float*          qkvb = (float*)(BA + 0);                    // [2052,2304] f32
  unsigned short* obuf = (unsigned short*)(BA + 18911232);    // [2052,768] bf16
  unsigned short* mh   = (unsigned short*)(BA + 22063104);    // [2052,3072] bf16

  cvt_kernel<<<32, 256, 0, stream>>>(w1b, w1bb, 32768);
  cvt_kernel<<<256, 256, 0, stream>>>(w2a, w2ab, 262144);
  cvt_kernel<<<128, 256, 0, stream>>>(w2b, w2bb, 131072);
  cvt_kernel<<<192, 256, 0, stream>>>(e2t_w, e2tb, 196608);

  fps_kernel<<<BB, 512, 0, stream>>>(pts, fidx, center);
  knn_kernel<<<BB * GG, 256, 0, stream>>>(pts, center, knn);

  for (int c = 0; c < 4; c++) {
    int gbase = c * 512;
    enc1a_kernel<<<512, 256, 0, stream>>>(pts, colors, knn, center,
        w1a, b1a, bn1g, bn1b, bn1m, bn1v, f1, gbase);
    bgemm<0, 0, 1, 0><<<dim3(2, 128), 256, 0, stream>>>(f1, nullptr, w1bb, b1b,
        nullptr, f2, 16384, 256, 128, nullptr, nullptr, nullptr, nullptr);
    maxpool_kernel<<<512, 256, 0, stream>>>(f2, fg, 512 * 256);
    bgemm<2, 0, 1, 1><<<dim3(4, 128), 256, 0, stream>>>(f2, fg, w2ab, b2a,
        nullptr, f3, 16384, 512, 512, bn2g, bn2b, bn2m, bn2v);
    bgemm<0, 0, 1, 0><<<dim3(2, 128), 256, 0, stream>>>(f3, nullptr, w2bb, b2b,
        nullptr, f4, 16384, 256, 512, nullptr, nullptr, nullptr, nullptr);
    maxpool_kernel<<<512, 256, 0, stream>>>(f4, tok + (size_t)gbase * 256, 512 * 256);
  }

  bgemm<0, 0, 0, 0><<<dim3(6, 16), 256, 0, stream>>>(tok, nullptr, e2tb, e2t_b,
      nullptr, tp, 2048, 768, 256, nullptr, nullptr, nullptr, nullptr);
  pe_hidden_kernel<<<1024, 256, 0, stream>>>(center, pe_w1, pe_b1, hid);
  gemm_kernel<1, 0, 0><<<dim3(12, 32), 256, 0, stream>>>(hid, pe_w2, pe_b2, nullptr, pp, 2048, 768, 128);
  assemble_kernel<<<BB * SS, 256, 0, stream>>>(tp, pp, cls_token, cls_pos, xs);

  for (int i = 0; i < 4; i++) {
    tc_kernel<<<dim3(72, 24), 256, 0, stream>>>(qkv_w + (size_t)i * 768 * 2304, qkv_wt, 768, 2304);
    tc_kernel<<<dim3(24, 24), 256, 0, stream>>>(proj_w + (size_t)i * 768 * 768, proj_wt, 768, 768);
    tc_kernel<<<dim3(96, 24), 256, 0, stream>>>(mlp_w1 + (size_t)i * 768 * 3072, w1t, 768, 3072);
    tc_kernel<<<dim3(24, 96), 256, 0, stream>>>(mlp_w2 + (size_t)i * 3072 * 768, w2t, 3072, 768);

    ln_kernel<1><<<BB * SS, 256, 0, stream>>>(xs, ln1_g + i * 768, ln1_b + i * 768, hbuf);
    bgemm<0, 0, 0, 0><<<dim3(18, 17), 256, 0, stream>>>(hbuf, nullptr, qkv_wt,
        qkv_b + i * 2304, nullptr, qkvb, 2052, 2304, 768, nullptr, nullptr, nullptr, nullptr);
    flash_kernel<<<dim3(9, 12, 4), 256, 0, stream>>>(qkvb, obuf);
    bgemm<0, 1, 0, 0><<<dim3(6, 17), 256, 0, stream>>>(obuf, nullptr, proj_wt,
        proj_b + i * 768, xs, xs, 2052, 768, 768, nullptr, nullptr, nullptr, nullptr);
    ln_kernel<1><<<BB * SS, 256, 0, stream>>>(xs, ln2_g + i * 768, ln2_b + i * 768, hbuf);
    bgemm<1, 0, 1, 0><<<dim3(24, 17), 256, 0, stream>>>(hbuf, nullptr, w1t,
        mlp_b1 + i * 3072, nullptr, mh, 2052, 3072, 768, nullptr, nullptr, nullptr, nullptr);
    bgemm<0, 1, 0, 0><<<dim3(6, 17), 256, 0, stream>>>(mh, nullptr, w2t,
        mlp_b2 + i * 768, xs, xs, 2052, 768, 3072, nullptr, nullptr, nullptr, nullptr);
  }

  ln_kernel<0><<<BB * SS, 256, 0, stream>>>(xs, fcn_g, fcn_b, fbuf);
  gemm_kernel<1, 0, 0><<<dim3(12, 33), 256, 0, stream>>>(fbuf, t2e_w, t2e_b, nullptr,
      (float*)d_out, 2052, 768, 768);
}